// Round 13
// baseline (763.508 us; speedup 1.0000x reference)
//
#include <hip/hip_runtime.h>
#include <cstdint>
#include <cstddef>

// Problem constants
#define BB   4
#define TT   1024
#define CC   1024
#define HH   16
#define HSS  64
#define NNtok 4096            // B*T
#define EPSGN 0.00064f
#define W2TS 192              // W2TB col count (maa_w2 128 | decay_w2 64)

typedef unsigned short bf16u;
typedef __attribute__((ext_vector_type(8))) short short8;
typedef __attribute__((ext_vector_type(4))) float f32x4;
#define SLOT 4194304ull       // elements per 8MiB bf16 slot (= NNtok*CC)

__device__ __forceinline__ float bf2f(bf16u u){
  union { unsigned int i; float f; } cv; cv.i = ((unsigned int)u) << 16; return cv.f;
}
__device__ __forceinline__ unsigned short f2bfbits(unsigned int x){
  return (unsigned short)((x + 0x7fffu + ((x >> 16) & 1u)) >> 16);   // RNE
}
__device__ __forceinline__ bf16u f2bf(float f){
  union { float f; unsigned int i; } cv; cv.f = f;
  return f2bfbits(cv.i);
}
__device__ __forceinline__ void ld4bf(const bf16u* p, float* o){
  ushort4 u = *reinterpret_cast<const ushort4*>(p);
  o[0]=bf2f(u.x); o[1]=bf2f(u.y); o[2]=bf2f(u.z); o[3]=bf2f(u.w);
}
__device__ __forceinline__ void st4bf(bf16u* p, const float* v){
  ushort4 u; u.x=f2bf(v[0]); u.y=f2bf(v[1]); u.z=f2bf(v[2]); u.w=f2bf(v[3]);
  *reinterpret_cast<ushort4*>(p) = u;
}
__device__ __forceinline__ unsigned short f2h(float f){
  union { _Float16 h; unsigned short s; } c; c.h = (_Float16)f; return c.s;
}
__device__ __forceinline__ void st4h(bf16u* p, const float* v){
  ushort4 u; u.x=f2h(v[0]); u.y=f2h(v[1]); u.z=f2h(v[2]); u.w=f2h(v[3]);
  *reinterpret_cast<ushort4*>(p) = u;
}
__device__ __forceinline__ void ld4f(const float* p, float* o){
  float4 v = *reinterpret_cast<const float4*>(p);
  o[0]=v.x; o[1]=v.y; o[2]=v.z; o[3]=v.w;
}
__device__ __forceinline__ float sigm(float x){ return 1.f / (1.f + expf(-x)); }

// unpack helpers
__device__ __forceinline__ float bflo(unsigned int u){
  union { unsigned int i; float f; } c; c.i = u << 16; return c.f;
}
__device__ __forceinline__ float bfhi(unsigned int u){
  union { unsigned int i; float f; } c; c.i = u & 0xffff0000u; return c.f;
}
__device__ __forceinline__ float hlo(unsigned int u){
  union { unsigned short s; _Float16 h; } c; c.s = (unsigned short)(u & 0xffffu); return (float)c.h;
}
__device__ __forceinline__ float hhi(unsigned int u){
  union { unsigned short s; _Float16 h; } c; c.s = (unsigned short)(u >> 16); return (float)c.h;
}
__device__ __forceinline__ float hval(unsigned short s){
  union { unsigned short s; _Float16 h; } c; c.s = s; return (float)c.h;
}
__device__ __forceinline__ float dot4(const float* x, const float* y){
  return (x[0]*y[0] + x[1]*y[1]) + (x[2]*y[2] + x[3]*y[3]);
}

// 16-lane sum via DPP. old=0 + bound_ctrl=1 folds to single v_add_f32_dpp.
template<int CTRL>
__device__ __forceinline__ float dpp_add(float v){
  union { float f; int i; } a, b;
  a.f = v;
  b.i = __builtin_amdgcn_update_dpp(0, a.i, CTRL, 0xF, 0xF, true);
  return v + b.f;
}
__device__ __forceinline__ float red16(float v){
  v = dpp_add<0xB1>(v);    // quad_perm [1,0,3,2]  (xor 1)
  v = dpp_add<0x4E>(v);    // quad_perm [2,3,0,1]  (xor 2)
  v = dpp_add<0x124>(v);   // row_ror:4
  v = dpp_add<0x128>(v);   // row_ror:8
  return v;
}
// 32-lane sum in all lanes: red16 then exchange complementary 16-rows
// between two DISTINCT-register copies (laundered; rounds 1/3 failed when
// regalloc coalesced both operands into one phys reg -> self-swap).
__device__ __forceinline__ float red32(float v){
  v = red16(v);
  union { float f; int i; } x, y;
  x.f = v; y.f = v;
  asm volatile("" : "+v"(y.i));   // distinct-vreg launder
  asm volatile("v_permlane16_swap_b32 %0, %1" : "+v"(x.i), "+v"(y.i));
  return x.f + y.f;
}

// ---------------------------------------------------------------------------
// mix = x + (x[t-1]-x[t])*time_maa_x  (x[-1]=0), stored bf16 (fallback path)
// ---------------------------------------------------------------------------
__global__ __launch_bounds__(256) void k_prep(const float* __restrict__ x,
                                              const float* __restrict__ tmx,
                                              bf16u* __restrict__ MIX){
  int e = (blockIdx.x * 256 + threadIdx.x) * 4;
  int n = e >> 10;
  int c = e & (CC - 1);
  int t = n & (TT - 1);
  float xf[4]; ld4f(x + e, xf);
  float pf[4] = {0.f, 0.f, 0.f, 0.f};
  if (t > 0) ld4f(x + e - CC, pf);
  float tm[4]; ld4f(tmx + c, tm);
  float mv[4];
  #pragma unroll
  for (int i = 0; i < 4; ++i) mv[i] = xf[i] + (pf[i] - xf[i]) * tm[i];
  st4bf(MIX + e, mv);
}

// ---------------------------------------------------------------------------
// Weight pre-conversion (r13: mix removed — fused into lo GEMM staging).
// Outputs live in WF region (60..67.4 MiB), dead before k_elem at step 7.
// ---------------------------------------------------------------------------
__global__ __launch_bounds__(256) void k_wconv1(
    const float* __restrict__ Wr, const float* __restrict__ Wk,
    const float* __restrict__ Wv,
    const float* __restrict__ maa_w1, const float* __restrict__ gate_w1,
    const float* __restrict__ decay_w1, const float* __restrict__ aaa_w1,
    const float* __restrict__ ma_w1, const float* __restrict__ kkk_w1,
    const float* __restrict__ mk_w1,
    const float* __restrict__ maa_w2, const float* __restrict__ decay_w2,
    bf16u* __restrict__ WrB, bf16u* __restrict__ WkB, bf16u* __restrict__ WvB,
    bf16u* __restrict__ W1B, bf16u* __restrict__ W2TB){
  int blk = blockIdx.x, tid = threadIdx.x;
  if (blk < 3072){
    const float* src = (blk < 1024) ? Wr : (blk < 2048) ? Wk : Wv;
    bf16u* dst = (blk < 1024) ? WrB : (blk < 2048) ? WkB : WvB;
    size_t e = (size_t)(blk & 1023) * 1024 + (size_t)tid * 4;
    float v[4]; ld4f(src + e, v);
    st4bf(dst + e, v);
  } else if (blk < 3456){
    int row = blk - 3072;
    const float* src;
    if      (row < 128) src = maa_w1   + (size_t)row * 1024;
    else if (row < 256) src = gate_w1  + (size_t)(row - 128) * 1024;
    else if (row < 320) src = decay_w1 + (size_t)(row - 256) * 1024;
    else if (row < 336) src = aaa_w1   + (size_t)(row - 320) * 1024;
    else if (row < 352) src = ma_w1    + (size_t)(row - 336) * 1024;
    else if (row < 368) src = kkk_w1   + (size_t)(row - 352) * 1024;
    else                src = mk_w1    + (size_t)(row - 368) * 1024;
    float v[4]; ld4f(src + tid * 4, v);
    st4bf(W1B + (size_t)row * 1024 + tid * 4, v);
  } else {
    int j = blk - 3456;   // 0..191
    const float* src = (j < 128) ? (maa_w2 + (size_t)j * 1024)
                                 : (decay_w2 + (size_t)(j - 128) * 1024);
    for (int c = tid; c < 1024; c += 256)
      W2TB[(size_t)c * W2TS + j] = f2bf(src[c]);
  }
}

// ---------------------------------------------------------------------------
// MFMA NT GEMM body, bf16-W, M64xN128, BK=64 double-K staging.
// ---------------------------------------------------------------------------
#define B64_AROW 72
#define B64_ASZ (64*72)
#define B64_BSZ (128*72)
template<bool OB>
__device__ __forceinline__ void gemm_b64_body(const bf16u* __restrict__ X,
                                              const bf16u* __restrict__ WB,
                                              void* __restrict__ OUTv,
                                              int Nd, int Kd, int act_n,
                                              short* __restrict__ As,
                                              short* __restrict__ Bs,
                                              int bn0, int bm0){
  const int tid  = threadIdx.x;
  const int lane = tid & 63;
  const int wv   = tid >> 6;
  const int wm   = wv >> 1, wn = wv & 1;   // wave -> 32-row x 64-col subtile
  const int l15  = lane & 15;
  const int quad = lane >> 4;

  f32x4 acc[2][4];
  #pragma unroll
  for (int mi = 0; mi < 2; ++mi)
    #pragma unroll
    for (int ni = 0; ni < 4; ++ni)
      #pragma unroll
      for (int rg = 0; rg < 4; ++rg) acc[mi][ni][rg] = 0.f;

  const int ra = tid >> 2, k0a = (tid & 3) * 16;   // A: 64 rows x 64k, 2 uint4/thr
  const int rb = tid >> 1, k0b = (tid & 1) * 32;   // B: 128 rows x 64k, 4 uint4/thr
  const bf16u* xsrc = X + (size_t)(bm0 + ra) * Kd;
  const bf16u* wsrc = (bn0 + rb < Nd) ? WB + (size_t)(bn0 + rb) * Kd : nullptr;

  uint4 xa0 = *(const uint4*)(xsrc + k0a);
  uint4 xa1 = *(const uint4*)(xsrc + k0a + 8);
  uint4 wa0 = make_uint4(0,0,0,0), wa1 = wa0, wa2 = wa0, wa3 = wa0;
  if (wsrc){
    wa0 = *(const uint4*)(wsrc + k0b);
    wa1 = *(const uint4*)(wsrc + k0b + 8);
    wa2 = *(const uint4*)(wsrc + k0b + 16);
    wa3 = *(const uint4*)(wsrc + k0b + 24);
  }
  *(uint4*)&As[ra * B64_AROW + k0a]      = xa0;
  *(uint4*)&As[ra * B64_AROW + k0a + 8]  = xa1;
  *(uint4*)&Bs[rb * B64_AROW + k0b]      = wa0;
  *(uint4*)&Bs[rb * B64_AROW + k0b + 8]  = wa1;
  *(uint4*)&Bs[rb * B64_AROW + k0b + 16] = wa2;
  *(uint4*)&Bs[rb * B64_AROW + k0b + 24] = wa3;
  __syncthreads();

  const int NS = Kd >> 6;
  for (int s = 0; s < NS; ++s){
    const int cur = s & 1;
    if (s + 1 < NS){                    // issue next-stage loads BEFORE compute
      int kb = (s + 1) << 6;
      xa0 = *(const uint4*)(xsrc + kb + k0a);
      xa1 = *(const uint4*)(xsrc + kb + k0a + 8);
      if (wsrc){
        wa0 = *(const uint4*)(wsrc + kb + k0b);
        wa1 = *(const uint4*)(wsrc + kb + k0b + 8);
        wa2 = *(const uint4*)(wsrc + kb + k0b + 16);
        wa3 = *(const uint4*)(wsrc + kb + k0b + 24);
      }
    }
    #pragma unroll
    for (int kk = 0; kk < 64; kk += 32){
      short8 af[2], bfg[4];
      #pragma unroll
      for (int mi = 0; mi < 2; ++mi)
        af[mi] = *(const short8*)&As[cur*B64_ASZ + (wm*32 + mi*16 + l15) * B64_AROW + kk + quad*8];
      #pragma unroll
      for (int ni = 0; ni < 4; ++ni)
        bfg[ni] = *(const short8*)&Bs[cur*B64_BSZ + (wn*64 + ni*16 + l15) * B64_AROW + kk + quad*8];
      #pragma unroll
      for (int mi = 0; mi < 2; ++mi)
        #pragma unroll
        for (int ni = 0; ni < 4; ++ni)
          acc[mi][ni] = __builtin_amdgcn_mfma_f32_16x16x32_bf16(af[mi], bfg[ni], acc[mi][ni], 0, 0, 0);
    }
    if (s + 1 < NS){
      const int nxt = cur ^ 1;
      *(uint4*)&As[nxt*B64_ASZ + ra * B64_AROW + k0a]      = xa0;
      *(uint4*)&As[nxt*B64_ASZ + ra * B64_AROW + k0a + 8]  = xa1;
      *(uint4*)&Bs[nxt*B64_BSZ + rb * B64_AROW + k0b]      = wa0;
      *(uint4*)&Bs[nxt*B64_BSZ + rb * B64_AROW + k0b + 8]  = wa1;
      *(uint4*)&Bs[nxt*B64_BSZ + rb * B64_AROW + k0b + 16] = wa2;
      *(uint4*)&Bs[nxt*B64_BSZ + rb * B64_AROW + k0b + 24] = wa3;
      __syncthreads();
    }
  }

  #pragma unroll
  for (int mi = 0; mi < 2; ++mi){
    #pragma unroll
    for (int ni = 0; ni < 4; ++ni){
      int col = bn0 + wn*64 + ni*16 + l15;
      if (col >= Nd) continue;
      #pragma unroll
      for (int rg = 0; rg < 4; ++rg){
        int row = bm0 + wm*32 + mi*16 + quad*4 + rg;
        float v = acc[mi][ni][rg];
        if (col < act_n) v = tanhf(v);
        if (OB) ((bf16u*)OUTv)[(size_t)row * Nd + col] = f2bf(v);
        else    ((float*)OUTv)[(size_t)row * Nd + col] = v;
      }
    }
  }
}

template<bool OB>
__global__ __launch_bounds__(256) void k_gemm_b64(const bf16u* __restrict__ X,
                                                  const bf16u* __restrict__ WB,
                                                  void* __restrict__ OUTv,
                                                  int Nd, int Kd, int act_n){
  __shared__ short As[2*B64_ASZ];
  __shared__ short Bs[2*B64_BSZ];
  gemm_b64_body<OB>(X, WB, OUTv, Nd, Kd, act_n, As, Bs,
                    blockIdx.x * 128, blockIdx.y * 64);
}

// ---------------------------------------------------------------------------
// lo GEMM with FUSED mix staging (r13): A elements computed on the fly from
// x (mix = x + (x[t-1]-x[t])*tmx, f2bf RNE) — identical bits to the old
// MIX buffer, but the 4096-block mix pass and its 16MB of traffic vanish.
// ---------------------------------------------------------------------------
__device__ __forceinline__ void mix16(const float* __restrict__ x,
                                      const float* __restrict__ tmx,
                                      int n, int k0, uint4* o0, uint4* o1){
  size_t e = (size_t)n * CC + k0;
  int t = n & (TT - 1);
  union { unsigned short s[8]; uint4 v; } p0, p1;
  #pragma unroll
  for (int i = 0; i < 16; i += 4){
    float xf[4]; ld4f(x + e + i, xf);
    float pf[4] = {0.f, 0.f, 0.f, 0.f};
    if (t > 0) ld4f(x + e + i - CC, pf);
    float tm[4]; ld4f(tmx + k0 + i, tm);
    #pragma unroll
    for (int j = 0; j < 4; ++j){
      float mv = xf[j] + (pf[j] - xf[j]) * tm[j];
      unsigned short b = f2bf(mv);
      if (i + j < 8) p0.s[i + j] = b; else p1.s[i + j - 8] = b;
    }
  }
  *o0 = p0.v; *o1 = p1.v;
}

__global__ __launch_bounds__(256) void k_gemm_b64_mix(
    const float* __restrict__ x, const float* __restrict__ tmx,
    const bf16u* __restrict__ WB, bf16u* __restrict__ OUT,
    int Nd, int act_n){
  __shared__ short As[2*B64_ASZ];
  __shared__ short Bs[2*B64_BSZ];
  const int Kd = CC;
  const int tid  = threadIdx.x;
  const int lane = tid & 63;
  const int wv   = tid >> 6;
  const int wm   = wv >> 1, wn = wv & 1;
  const int bn0  = blockIdx.x * 128;
  const int bm0  = blockIdx.y * 64;
  const int l15  = lane & 15;
  const int quad = lane >> 4;

  f32x4 acc[2][4];
  #pragma unroll
  for (int mi = 0; mi < 2; ++mi)
    #pragma unroll
    for (int ni = 0; ni < 4; ++ni)
      #pragma unroll
      for (int rg = 0; rg < 4; ++rg) acc[mi][ni][rg] = 0.f;

  const int ra = tid >> 2, k0a = (tid & 3) * 16;
  const int rb = tid >> 1, k0b = (tid & 1) * 32;
  const int an = bm0 + ra;                       // token index for mix
  const bf16u* wsrc = (bn0 + rb < Nd) ? WB + (size_t)(bn0 + rb) * Kd : nullptr;

  uint4 xa0, xa1;
  mix16(x, tmx, an, k0a, &xa0, &xa1);
  uint4 wa0 = make_uint4(0,0,0,0), wa1 = wa0, wa2 = wa0, wa3 = wa0;
  if (wsrc){
    wa0 = *(const uint4*)(wsrc + k0b);
    wa1 = *(const uint4*)(wsrc + k0b + 8);
    wa2 = *(const uint4*)(wsrc + k0b + 16);
    wa3 = *(const uint4*)(wsrc + k0b + 24);
  }
  *(uint4*)&As[ra * B64_AROW + k0a]      = xa0;
  *(uint4*)&As[ra * B64_AROW + k0a + 8]  = xa1;
  *(uint4*)&Bs[rb * B64_AROW + k0b]      = wa0;
  *(uint4*)&Bs[rb * B64_AROW + k0b + 8]  = wa1;
  *(uint4*)&Bs[rb * B64_AROW + k0b + 16] = wa2;
  *(uint4*)&Bs[rb * B64_AROW + k0b + 24] = wa3;
  __syncthreads();

  const int NS = Kd >> 6;
  for (int s = 0; s < NS; ++s){
    const int cur = s & 1;
    if (s + 1 < NS){
      int kb = (s + 1) << 6;
      mix16(x, tmx, an, kb + k0a, &xa0, &xa1);
      if (wsrc){
        wa0 = *(const uint4*)(wsrc + kb + k0b);
        wa1 = *(const uint4*)(wsrc + kb + k0b + 8);
        wa2 = *(const uint4*)(wsrc + kb + k0b + 16);
        wa3 = *(const uint4*)(wsrc + kb + k0b + 24);
      }
    }
    #pragma unroll
    for (int kk = 0; kk < 64; kk += 32){
      short8 af[2], bfg[4];
      #pragma unroll
      for (int mi = 0; mi < 2; ++mi)
        af[mi] = *(const short8*)&As[cur*B64_ASZ + (wm*32 + mi*16 + l15) * B64_AROW + kk + quad*8];
      #pragma unroll
      for (int ni = 0; ni < 4; ++ni)
        bfg[ni] = *(const short8*)&Bs[cur*B64_BSZ + (wn*64 + ni*16 + l15) * B64_AROW + kk + quad*8];
      #pragma unroll
      for (int mi = 0; mi < 2; ++mi)
        #pragma unroll
        for (int ni = 0; ni < 4; ++ni)
          acc[mi][ni] = __builtin_amdgcn_mfma_f32_16x16x32_bf16(af[mi], bfg[ni], acc[mi][ni], 0, 0, 0);
    }
    if (s + 1 < NS){
      const int nxt = cur ^ 1;
      *(uint4*)&As[nxt*B64_ASZ + ra * B64_AROW + k0a]      = xa0;
      *(uint4*)&As[nxt*B64_ASZ + ra * B64_AROW + k0a + 8]  = xa1;
      *(uint4*)&Bs[nxt*B64_BSZ + rb * B64_AROW + k0b]      = wa0;
      *(uint4*)&Bs[nxt*B64_BSZ + rb * B64_AROW + k0b + 8]  = wa1;
      *(uint4*)&Bs[nxt*B64_BSZ + rb * B64_AROW + k0b + 16] = wa2;
      *(uint4*)&Bs[nxt*B64_BSZ + rb * B64_AROW + k0b + 24] = wa3;
      __syncthreads();
    }
  }

  #pragma unroll
  for (int mi = 0; mi < 2; ++mi){
    #pragma unroll
    for (int ni = 0; ni < 4; ++ni){
      int col = bn0 + wn*64 + ni*16 + l15;
      if (col >= Nd) continue;
      #pragma unroll
      for (int rg = 0; rg < 4; ++rg){
        int row = bm0 + wm*32 + mi*16 + quad*4 + rg;
        float v = acc[mi][ni][rg];
        if (col < act_n) v = tanhf(v);
        OUT[(size_t)row * Nd + col] = f2bf(v);
      }
    }
  }
}

// R/K/V big projections merged into one z=3 launch.
__global__ __launch_bounds__(256) void k_gemm_b64_rkv(const bf16u* __restrict__ X0,
                                                      const bf16u* __restrict__ X2,
                                                      const bf16u* __restrict__ X3,
                                                      const bf16u* __restrict__ WrB,
                                                      const bf16u* __restrict__ WkB,
                                                      const bf16u* __restrict__ WvB,
                                                      bf16u* __restrict__ R,
                                                      bf16u* __restrict__ K0,
                                                      bf16u* __restrict__ V){
  __shared__ short As[2*B64_ASZ];
  __shared__ short Bs[2*B64_BSZ];
  const int z = blockIdx.z;
  const int bn0 = blockIdx.x * 128, bm0 = blockIdx.y * 64;
  if (z == 0)      gemm_b64_body<true>(X0, WrB, R,  CC, CC, 0, As, Bs, bn0, bm0);
  else if (z == 1) gemm_b64_body<true>(X2, WkB, K0, CC, CC, 0, As, Bs, bn0, bm0);
  else             gemm_b64_body<true>(X3, WvB, V,  CC, CC, 0, As, Bs, bn0, bm0);
}

// 3 LoRA projections merged into one launch (z decodes).
__global__ __launch_bounds__(256) void k_gemm_b64_lora(const bf16u* __restrict__ X0,
                                                       const bf16u* __restrict__ X1,
                                                       const bf16u* __restrict__ X2,
                                                       const bf16u* __restrict__ W1B,
                                                       bf16u* __restrict__ GT,
                                                       bf16u* __restrict__ P1,
                                                       bf16u* __restrict__ P2){
  __shared__ short As[2*B64_ASZ];
  __shared__ short Bs[2*B64_BSZ];
  const int z = blockIdx.z;
  const int bm0 = blockIdx.y * 64;
  if (z == 0)
    gemm_b64_body<true>(X0, W1B + 128*1024, GT, 128, CC, 128, As, Bs, 0, bm0);
  else if (z == 1)
    gemm_b64_body<true>(X1, W1B + 256*1024, P1, 96, CC, 64, As, Bs, 0, bm0);
  else
    gemm_b64_body<true>(X2, W1B + 352*1024, P2, 32, CC, 16, As, Bs, 0, bm0);
}

// ---------------------------------------------------------------------------
// MFMA NN GEMM body, pre-transposed bf16 B (single-staging; K fits in LDS).
// ---------------------------------------------------------------------------
template<int KD, int EP>
__device__ __forceinline__ void gemm_nn_body(const bf16u* __restrict__ A, int lda,
                                             const bf16u* __restrict__ BT, int koff,
                                             bf16u* __restrict__ OUT,
                                             const float* __restrict__ x,
                                             const float* __restrict__ tma_g,
                                             short* __restrict__ As,
                                             short* __restrict__ Bs,
                                             int bn0, int bm0){
  const int tid  = threadIdx.x;
  const int lane = tid & 63;
  const int wv   = tid >> 6;
  const int wm   = wv >> 1, wn = wv & 1;
  const int l15  = lane & 15;
  const int quad = lane >> 4;

  for (int idx = tid; idx < 128 * (KD / 8); idx += 256){
    int r  = idx / (KD / 8);
    int kc = (idx % (KD / 8)) * 8;
    *(uint4*)&As[r * (KD + 8) + kc] =
        *(const uint4*)(A + (size_t)(bm0 + r) * lda + kc);
  }
  for (int idx = tid; idx < 128 * (KD / 8); idx += 256){
    int cc_ = idx / (KD / 8);
    int kc  = (idx % (KD / 8)) * 8;
    *(uint4*)&Bs[cc_ * (KD + 8) + kc] =
        *(const uint4*)(BT + (size_t)(bn0 + cc_) * W2TS + koff + kc);
  }
  __syncthreads();

  f32x4 acc[4][4];
  #pragma unroll
  for (int mi = 0; mi < 4; ++mi)
    #pragma unroll
    for (int ni = 0; ni < 4; ++ni)
      #pragma unroll
      for (int rg = 0; rg < 4; ++rg) acc[mi][ni][rg] = 0.f;

  #pragma unroll
  for (int kk = 0; kk < KD; kk += 32){
    short8 af[4], bfg[4];
    #pragma unroll
    for (int mi = 0; mi < 4; ++mi)
      af[mi] = *(const short8*)&As[(wm*64 + mi*16 + l15) * (KD + 8) + kk + quad*8];
    #pragma unroll
    for (int ni = 0; ni < 4; ++ni)
      bfg[ni] = *(const short8*)&Bs[(wn*64 + ni*16 + l15) * (KD + 8) + kk + quad*8];
    #pragma unroll
    for (int mi = 0; mi < 4; ++mi)
      #pragma unroll
      for (int ni = 0; ni < 4; ++ni)
        acc[mi][ni] = __builtin_amdgcn_mfma_f32_16x16x32_bf16(af[mi], bfg[ni], acc[mi][ni], 0, 0, 0);
  }

  #pragma unroll
  for (int mi = 0; mi < 4; ++mi){
    #pragma unroll
    for (int ni = 0; ni < 4; ++ni){
      int col = bn0 + wn*64 + ni*16 + l15;
      float tm = (EP == 1) ? tma_g[col] : 0.f;
      #pragma unroll
      for (int rg = 0; rg < 4; ++rg){
        int row = bm0 + wm*64 + mi*16 + quad*4 + rg;
        float v = acc[mi][ni][rg];
        if (EP == 1){
          float xv = x[(size_t)row * CC + col];
          float xp = ((row & (TT - 1)) == 0) ? 0.f : x[(size_t)row * CC + col - CC];
          v = xv + (xp - xv) * (v + tm);
        }
        OUT[(size_t)row * CC + col] = f2bf(v);
      }
    }
  }
}

template<int KD, int EP>
__global__ __launch_bounds__(256) void k_gemm_nn_b(const bf16u* __restrict__ A, int lda,
                                                   const bf16u* __restrict__ BT, int koff,
                                                   bf16u* __restrict__ OUT,
                                                   const float* __restrict__ x,
                                                   const float* __restrict__ tma_g){
  __shared__ short As[128 * (KD + 8)];
  __shared__ short Bs[128 * (KD + 8)];
  gemm_nn_body<KD, EP>(A, lda, BT, koff, OUT, x, tma_g, As, Bs,
                       blockIdx.x * 128, blockIdx.y * 128);
}

// 4 xm NN-GEMMs merged into one launch (z = group).
__global__ __launch_bounds__(256) void k_gemm_nn_b4(const bf16u* __restrict__ LO,
                                                    const bf16u* __restrict__ BT,
                                                    bf16u* __restrict__ X0base,
                                                    const float* __restrict__ x,
                                                    const float* __restrict__ tmaa){
  __shared__ short As[128 * 40];
  __shared__ short Bs[128 * 40];
  const int z = blockIdx.z;
  gemm_nn_body<32, 1>(LO + z*32, 128, BT, z*32, X0base + (size_t)z*SLOT,
                      x, tmaa + (size_t)z*CC, As, Bs,
                      blockIdx.x * 128, blockIdx.y * 128);
}

// ---------------------------------------------------------------------------
// LEGACY f32-W GEMMs (fallback path only)
// ---------------------------------------------------------------------------
template<bool OB>
__global__ __launch_bounds__(256) void k_gemm_mfma(const bf16u* __restrict__ X,
                                                   const float* __restrict__ Wa,
                                                   const float* __restrict__ Wb,
                                                   const float* __restrict__ Wc,
                                                   int na, int nab,
                                                   void* __restrict__ OUTv,
                                                   int Nd, int Kd, int act_n){
  __shared__ short As[128 * 40];
  __shared__ short Bs[128 * 40];
  const int tid  = threadIdx.x;
  const int lane = tid & 63;
  const int wv   = tid >> 6;
  const int wm   = wv >> 1, wn = wv & 1;
  const int bn0  = blockIdx.x * 128;
  const int bm0  = blockIdx.y * 128;
  const int l15  = lane & 15;
  const int quad = lane >> 4;

  f32x4 acc[4][4];
  #pragma unroll
  for (int mi = 0; mi < 4; ++mi)
    #pragma unroll
    for (int ni = 0; ni < 4; ++ni)
      #pragma unroll
      for (int rg = 0; rg < 4; ++rg) acc[mi][ni][rg] = 0.f;

  const int r    = tid >> 1;
  const int half = (tid & 1) * 16;

  int rr = bn0 + r;
  const float* wsrc = nullptr;
  if (rr < na)        wsrc = Wa + (size_t)rr * Kd;
  else if (rr < nab)  wsrc = Wb + (size_t)(rr - na) * Kd;
  else if (rr < Nd)   wsrc = Wc + (size_t)(rr - nab) * Kd;
  const bf16u* xsrc = X + (size_t)(bm0 + r) * Kd;

  for (int k0 = 0; k0 < Kd; k0 += 32){
    uint4 xa = *(const uint4*)(xsrc + k0 + half);
    uint4 xb = *(const uint4*)(xsrc + k0 + half + 8);
    uint4 w0 = make_uint4(0,0,0,0), w1 = w0, w2 = w0, w3 = w0;
    if (wsrc){
      w0 = *(const uint4*)(wsrc + k0 + half);
      w1 = *(const uint4*)(wsrc + k0 + half + 4);
      w2 = *(const uint4*)(wsrc + k0 + half + 8);
      w3 = *(const uint4*)(wsrc + k0 + half + 12);
    }
    union { unsigned short s[8]; uint4 v; } p0, p1;
    p0.s[0]=f2bfbits(w0.x); p0.s[1]=f2bfbits(w0.y); p0.s[2]=f2bfbits(w0.z); p0.s[3]=f2bfbits(w0.w);
    p0.s[4]=f2bfbits(w1.x); p0.s[5]=f2bfbits(w1.y); p0.s[6]=f2bfbits(w1.z); p0.s[7]=f2bfbits(w1.w);
    p1.s[0]=f2bfbits(w2.x); p1.s[1]=f2bfbits(w2.y); p1.s[2]=f2bfbits(w2.z); p1.s[3]=f2bfbits(w2.w);
    p1.s[4]=f2bfbits(w3.x); p1.s[5]=f2bfbits(w3.y); p1.s[6]=f2bfbits(w3.z); p1.s[7]=f2bfbits(w3.w);

    *(uint4*)&As[r * 40 + half]     = xa;
    *(uint4*)&As[r * 40 + half + 8] = xb;
    *(uint4*)&Bs[r * 40 + half]     = p0.v;
    *(uint4*)&Bs[r * 40 + half + 8] = p1.v;
    __syncthreads();

    short8 af[4], bfg[4];
    #pragma unroll
    for (int mi = 0; mi < 4; ++mi)
      af[mi] = *(const short8*)&As[(wm*64 + mi*16 + l15) * 40 + quad*8];
    #pragma unroll
    for (int ni = 0; ni < 4; ++ni)
      bfg[ni] = *(const short8*)&Bs[(wn*64 + ni*16 + l15) * 40 + quad*8];
    #pragma unroll
    for (int mi = 0; mi < 4; ++mi)
      #pragma unroll
      for (int ni = 0; ni < 4; ++ni)
        acc[mi][ni] = __builtin_amdgcn_mfma_f32_16x16x32_bf16(af[mi], bfg[ni], acc[mi][ni], 0, 0, 0);
    __syncthreads();
  }

  #pragma unroll
  for (int mi = 0; mi < 4; ++mi){
    #pragma unroll
    for (int ni = 0; ni < 4; ++ni){
      int col = bn0 + wn*64 + ni*16 + l15;
      if (col >= Nd) continue;
      #pragma unroll
      for (int rg = 0; rg < 4; ++rg){
        int row = bm0 + wm*64 + mi*16 + quad*4 + rg;
        float v = acc[mi][ni][rg];
        if (col < act_n) v = tanhf(v);
        if (OB) ((bf16u*)OUTv)[(size_t)row * Nd + col] = f2bf(v);
        else    ((float*)OUTv)[(size_t)row * Nd + col] = v;
      }
    }
  }
}

template<int KD, int EP>
__global__ __launch_bounds__(256) void k_gemm_nn(const bf16u* __restrict__ A, int lda,
                                                 const float* __restrict__ B,
                                                 bf16u* __restrict__ OUT,
                                                 const float* __restrict__ x,
                                                 const float* __restrict__ tma_g){
  __shared__ short As[128 * (KD + 8)];
  __shared__ short Bs[128 * (KD + 8)];
  const int tid  = threadIdx.x;
  const int lane = tid & 63;
  const int wv   = tid >> 6;
  const int wm   = wv >> 1, wn = wv & 1;
  const int bn0  = blockIdx.x * 128;
  const int bm0  = blockIdx.y * 128;
  const int l15  = lane & 15;
  const int quad = lane >> 4;

  for (int idx = tid; idx < 128 * (KD / 8); idx += 256){
    int r  = idx / (KD / 8);
    int kc = (idx % (KD / 8)) * 8;
    *(uint4*)&As[r * (KD + 8) + kc] =
        *(const uint4*)(A + (size_t)(bm0 + r) * lda + kc);
  }
  for (int idx = tid; idx < KD * 128; idx += 256){
    int k = idx >> 7, c = idx & 127;
    Bs[c * (KD + 8) + k] = (short)f2bf(B[(size_t)k * CC + bn0 + c]);
  }
  __syncthreads();

  f32x4 acc[4][4];
  #pragma unroll
  for (int mi = 0; mi < 4; ++mi)
    #pragma unroll
    for (int ni = 0; ni < 4; ++ni)
      #pragma unroll
      for (int rg = 0; rg < 4; ++rg) acc[mi][ni][rg] = 0.f;

  #pragma unroll
  for (int kk = 0; kk < KD; kk += 32){
    short8 af[4], bfg[4];
    #pragma unroll
    for (int mi = 0; mi < 4; ++mi)
      af[mi] = *(const short8*)&As[(wm*64 + mi*16 + l15) * (KD + 8) + kk + quad*8];
    #pragma unroll
    for (int ni = 0; ni < 4; ++ni)
      bfg[ni] = *(const short8*)&Bs[(wn*64 + ni*16 + l15) * (KD + 8) + kk + quad*8];
    #pragma unroll
    for (int mi = 0; mi < 4; ++mi)
      #pragma unroll
      for (int ni = 0; ni < 4; ++ni)
        acc[mi][ni] = __builtin_amdgcn_mfma_f32_16x16x32_bf16(af[mi], bfg[ni], acc[mi][ni], 0, 0, 0);
  }

  #pragma unroll
  for (int mi = 0; mi < 4; ++mi){
    #pragma unroll
    for (int ni = 0; ni < 4; ++ni){
      int col = bn0 + wn*64 + ni*16 + l15;
      float tm = (EP == 1) ? tma_g[col] : 0.f;
      #pragma unroll
      for (int rg = 0; rg < 4; ++rg){
        int row = bm0 + wm*64 + mi*16 + quad*4 + rg;
        float v = acc[mi][ni][rg];
        if (EP == 1){
          float xv = x[(size_t)row * CC + col];
          float xp = ((row & (TT - 1)) == 0) ? 0.f : x[(size_t)row * CC + col - CC];
          v = xv + (xp - xv) * (v + tm);
        }
        OUT[(size_t)row * CC + col] = f2bf(v);
      }
    }
  }
}

// ---------------------------------------------------------------------------
// Fused elementwise + pair precompute + (fast path) Wo/gate_w2 conversion.
// Blocks >=1024 convert Wo -> WoB (S2) and gate_w2 -> GW2T (S2+2MiB); both
// regions dead in fast path (UX unused) -> one fewer launch, no phase hazard.
// WMODE=1: w_t stored exact f32 in WF. WMODE=0: f16 -u fallback (grid 1024).
// ---------------------------------------------------------------------------
template<int WMODE>
__global__ __launch_bounds__(256) void k_elem(bf16u* __restrict__ K0,
    const bf16u* __restrict__ P1, const bf16u* __restrict__ P2,
    const bf16u* __restrict__ W2A,
    const float* __restrict__ kw2, const float* __restrict__ aw2,
    const float* __restrict__ maw2, const float* __restrict__ mkw2,
    const float* __restrict__ td,  const float* __restrict__ taa,
    const float* __restrict__ tma, const float* __restrict__ tmk,
    const float* __restrict__ faaaa,
    bf16u* __restrict__ KKN, bf16u* __restrict__ Bb, bf16u* __restrict__ UX,
    float* __restrict__ WF,
    bf16u* __restrict__ Rq, float* __restrict__ Dsc, float* __restrict__ RKsc,
    const float* __restrict__ Wo, const float* __restrict__ gate_w2,
    bf16u* __restrict__ WoB, bf16u* __restrict__ GW2T){
  int tid = threadIdx.x;
  if (blockIdx.x >= 1024){
    int blk = blockIdx.x - 1024;
    if (blk < 1024){
      size_t e = ((size_t)blk * 256 + tid) * 4;
      float v[4]; ld4f(Wo + e, v);
      st4bf(WoB + e, v);
    } else {
      int c = (blk - 1024) * 2 + (tid >> 7);
      int j = tid & 127;
      GW2T[(size_t)c * 128 + j] = f2bf(gate_w2[(size_t)j * CC + c]);
    }
    return;
  }
  int n0 = blockIdx.x * 4;
  __shared__ float at_l[4][16], mat_l[4][16], kt_l[4][16], mkt_l[4][16];
  {
    int grp = tid >> 6, q = tid & 63, tt = q >> 4, j = q & 15;
    if (grp == 0)      at_l[tt][j]  = bf2f(P1[(size_t)(n0+tt)*96 + 64 + j]);
    else if (grp == 1) mat_l[tt][j] = bf2f(P1[(size_t)(n0+tt)*96 + 80 + j]);
    else if (grp == 2) kt_l[tt][j]  = bf2f(P2[(size_t)(n0+tt)*32 + j]);
    else               mkt_l[tt][j] = bf2f(P2[(size_t)(n0+tt)*32 + 16 + j]);
  }
  __syncthreads();
  int c  = tid * 4;
  int h  = tid >> 4;       // head (16 lanes per head)
  int lg = tid & 15;

  float kkk[4][4], aa[4][4], mam[4][4], mkm[4][4];
  #pragma unroll
  for (int tt = 0; tt < 4; ++tt)
    #pragma unroll
    for (int i = 0; i < 4; ++i){ kkk[tt][i]=0; aa[tt][i]=0; mam[tt][i]=0; mkm[tt][i]=0; }

  #pragma unroll 4
  for (int j = 0; j < 16; ++j){
    float wk[4], wa[4], wm[4], wq[4];
    ld4f(kw2  + (size_t)j*CC + c, wk);
    ld4f(aw2  + (size_t)j*CC + c, wa);
    ld4f(maw2 + (size_t)j*CC + c, wm);
    ld4f(mkw2 + (size_t)j*CC + c, wq);
    #pragma unroll
    for (int tt = 0; tt < 4; ++tt){
      float s1 = kt_l[tt][j], s2 = at_l[tt][j], s3 = mat_l[tt][j], s4 = mkt_l[tt][j];
      #pragma unroll
      for (int i = 0; i < 4; ++i){
        kkk[tt][i] += s1 * wk[i];
        aa[tt][i]  += s2 * wa[i];
        mam[tt][i] += s3 * wm[i];
        mkm[tt][i] += s4 * wq[i];
      }
    }
  }

  float td4[4], taa4[4], tma4[4], tmk4[4], fa4[4];
  ld4f(td + c, td4); ld4f(taa + c, taa4); ld4f(tma + c, tma4); ld4f(tmk + c, tmk4);
  ld4f(faaaa + c, fa4);

#define ELEM_TOKEN(TT_, E_, A_, B_, KF_, WD_) do{ \
    float k0a[4]; ld4bf(K0 + (E_), k0a); \
    float w2a[4]; ld4bf(W2A + (E_), w2a); \
    float ssq = 0.f; \
    _Pragma("unroll") \
    for (int i = 0; i < 4; ++i){ A_[i] = k0a[i] + kkk[TT_][i]; ssq += A_[i]*A_[i]; } \
    ssq = red16(ssq); \
    float rinv = 1.f / fmaxf(sqrtf(ssq), 1e-12f); \
    float outw_[4]; \
    _Pragma("unroll") \
    for (int i = 0; i < 4; ++i){ \
      float z  = td4[i] + w2a[i]; \
      float nz = -z; \
      float sp = (nz > 15.f) ? nz : log1pf(expf(nz)); \
      float w  = -sp - 0.5f; \
      float av  = sigm(taa4[i] + aa[TT_][i]); \
      float mav = sigm(tma4[i] + mam[TT_][i]); \
      float mkv = sigm(tmk4[i] + mkm[TT_][i]); \
      A_[i] *= rinv; \
      B_[i]  = -A_[i] * av; \
      KF_[i] = k0a[i] * (mav + av * (1.f - mav)) * expf(w * mkv); \
      float ou = -expf(w); \
      outw_[i] = ou; \
      if (WMODE == 1) WD_[i] = __expf(ou);              /* exact f32 w_t */ \
      else            WD_[i] = __expf(hval(f2h(ou)));   /* f16-consistent */ \
    } \
    st4bf(Bb + (E_), B_); \
    st4bf(K0 + (E_), KF_); \
    if (WMODE == 1) *(float4*)(WF + (E_)) = make_float4(WD_[0], WD_[1], WD_[2], WD_[3]); \
    else            st4h(UX + (E_), outw_); \
  }while(0)

  #pragma unroll
  for (int p = 0; p < 2; ++p){
    const int ttE = 2*p, ttO = ttE + 1;
    size_t eE = (size_t)(n0 + ttE) * CC + c;
    size_t eO = eE + CC;
    float aE[4], bE[4], kfE[4], wdE[4];
    float aO[4], bO[4], kfO[4], wdO[4];
    ELEM_TOKEN(ttE, eE, aE, bE, kfE, wdE);
    ELEM_TOKEN(ttO, eO, aO, bO, kfO, wdO);
    st4bf(KKN + eE, aE);

    float rE[4], rO[4];
    ld4bf(Rq + eE, rE); ld4bf(Rq + eO, rO);

    // rk for k_post (before R is overwritten)
    float rkE = red16(rE[0]*kfE[0]*fa4[0] + rE[1]*kfE[1]*fa4[1]
                    + rE[2]*kfE[2]*fa4[2] + rE[3]*kfE[3]*fa4[3]);
    float rkO = red16(rO[0]*kfO[0]*fa4[0] + rO[1]*kfO[1]*fa4[1]
                    + rO[2]*kfO[2]*fa4[2] + rO[3]*kfO[3]*fa4[3]);

    // u1 over KKN odd row
    float c1 = red16(dot4(bE, aO));
    float d  = red16(dot4(kfE, aO));
    float u1[4];
    #pragma unroll
    for (int i = 0; i < 4; ++i) u1[i] = wdE[i]*aO[i] + c1*aE[i];
    st4bf(KKN + eO, u1);

    // q' even
    float cq = red16(dot4(bE, rE));
    float e1 = red16(dot4(kfE, rE));
    float qe[4];
    #pragma unroll
    for (int i = 0; i < 4; ++i) qe[i] = wdE[i]*rE[i] + cq*aE[i];
    st4bf(Rq + eE, qe);

    // z = M_{t+1} q_{t+1}; q' odd = M_t z
    float cz  = red16(dot4(bO, rO));
    float e21 = red16(dot4(kfO, rO));
    float z[4];
    #pragma unroll
    for (int i = 0; i < 4; ++i) z[i] = wdO[i]*rO[i] + cz*aO[i];
    float cy  = red16(dot4(bE, z));
    float e20 = red16(dot4(kfE, z));
    float qo[4];
    #pragma unroll
    for (int i = 0; i < 4; ++i) qo[i] = wdE[i]*z[i] + cy*aE[i];
    st4bf(Rq + eO, qo);

    if (lg == 0){
      size_t pr = (size_t)((n0 + ttE) >> 1);
      float4 dv; dv.x = d; dv.y = e1; dv.z = e20; dv.w = e21;
      *(float4*)(Dsc + (pr * HH + h) * 4) = dv;
      RKsc[(size_t)(n0 + ttE) * HH + h] = rkE;
      RKsc[(size_t)(n0 + ttO) * HH + h] = rkO;
    }
  }
#undef ELEM_TOKEN
}

// ---------------------------------------------------------------------------
// Recurrence v13 (r8-validated): 32-lane rows, 2 waves/SIMD, pair-fused,
// all 4 reductions vs base S, f32 decay (WMODE=1).
// ---------------------------------------------------------------------------
template<int WMODE>
__global__ __launch_bounds__(256) void k_rec(const bf16u* __restrict__ Qp,
                                             const bf16u* __restrict__ WT,
                                             const float* __restrict__ WF,
                                             const bf16u* __restrict__ KFt,
                                             const bf16u* __restrict__ Vt,
                                             const bf16u* __restrict__ Aa,
                                             const bf16u* __restrict__ Bv,
                                             const float* __restrict__ Dsc,
                                             bf16u* __restrict__ Y){
  const int p   = blockIdx.x;                 // 0..511
  const int g   = (p & 7) | ((p >> 6) << 3);  // (b,h) group 0..63, XCD-clustered
  const int oct = (p >> 3) & 7;               // row octet within the head
  const int b   = g >> 4;
  const int h   = g & 15;
  const int tid = threadIdx.x;
  const int l31 = tid & 31;                   // 32 lanes per row
  const int i   = oct * 8 + (tid >> 5);       // state row 0..63
  const size_t base0 = (size_t)(b * TT) * CC + h * HSS;
  const size_t colb  = base0 + l31 * 2;       // 2 cols per lane
  const size_t rowb  = base0 + i;
  const size_t dscb  = ((size_t)(b * (TT/2)) * HH + h) * 4;

  float S0 = 0.f, S1 = 0.f;                   // state cols (2*l31, 2*l31+1)

  unsigned int qEA,qOA,aEA,uOA,kEA,kOA,bEA,bOA,wEA,wOA; float2 fEA,fOA; unsigned short vEA,vOA; float4 dA;
  unsigned int qEB,qOB,aEB,uOB,kEB,kOB,bEB,bOB,wEB,wOB; float2 fEB,fOB; unsigned short vEB,vOB; float4 dB;
  unsigned int qEC,qOC,aEC,uOC,kEC,kOC,bEC,bOC,wEC,wOC; float2 fEC,fOC; unsigned short vEC,vOC; float4 dC;
  unsigned int qED,qOD,aED,uOD,kED,kOD,bED,bOD,wED,wOD; float2 fED,fOD; unsigned short vED,vOD; float4 dD;

#define PL(S, T_) do{ \
    size_t cE_ = colb + (size_t)(T_) * CC, cO_ = cE_ + CC; \
    qE##S = *(const unsigned int*)(Qp  + cE_); qO##S = *(const unsigned int*)(Qp  + cO_); \
    aE##S = *(const unsigned int*)(Aa  + cE_); uO##S = *(const unsigned int*)(Aa  + cO_); \
    kE##S = *(const unsigned int*)(KFt + cE_); kO##S = *(const unsigned int*)(KFt + cO_); \
    bE##S = *(const unsigned int*)(Bv  + cE_); bO##S = *(const unsigned int*)(Bv  + cO_); \
    if (WMODE == 1){ \
      fE##S = *(const float2*)(WF + cE_); fO##S = *(const float2*)(WF + cO_); \
    } else { \
      wE##S = *(const unsigned int*)(WT + cE_); wO##S = *(const unsigned int*)(WT + cO_); \
    } \
    vE##S = Vt[rowb + (size_t)(T_) * CC]; \
    vO##S = Vt[rowb + (size_t)(T_ + 1) * CC]; \
    d##S  = *(const float4*)(Dsc + dscb + (size_t)((T_) >> 1) * (HH*4)); \
  }while(0)

#define PSTEP(S, T_) do{ \
    float a0=bflo(aE##S), a1=bfhi(aE##S); \
    float u0=bflo(uO##S), u1=bfhi(uO##S); \
    float g0=bflo(qE##S), g1=bfhi(qE##S); \
    float o0=bflo(qO##S), o1=bfhi(qO##S); \
    float pE_ = fmaf(S1, a1, S0 * a0); \
    float pO_ = fmaf(S1, u1, S0 * u0); \
    float yE_ = fmaf(S1, g1, S0 * g0); \
    float yO_ = fmaf(S1, o1, S0 * o0); \
    pE_ = red32(pE_); \
    pO_ = red32(pO_); \
    yE_ = red32(yE_); \
    yO_ = red32(yO_); \
    float vEf = bf2f(vE##S), vOf = bf2f(vO##S); \
    float saE = pE_; \
    float saO = fmaf(d##S.x, vEf, pO_); \
    float ypE = fmaf(d##S.y, vEf, yE_); \
    float ypO = fmaf(d##S.z, vEf, fmaf(d##S.w, vOf, yO_)); \
    float k0=bflo(kE##S), k1=bfhi(kE##S); \
    float b0=bflo(bE##S), b1=bfhi(bE##S); \
    float w0, w1; \
    if (WMODE == 1){ w0=fE##S.x; w1=fE##S.y; } \
    else { w0=__expf(hlo(wE##S)); w1=__expf(hhi(wE##S)); } \
    S0 = fmaf(S0, w0, fmaf(saE, b0, vEf * k0)); \
    S1 = fmaf(S1, w1, fmaf(saE, b1, vEf * k1)); \
    float ko0=bflo(kO##S), ko1=bfhi(kO##S); \
    float bo0=bflo(bO##S), bo1=bfhi(bO##S); \
    float wo0, wo1; \
    if (WMODE == 1){ wo0=fO##S.x; wo1=fO##S.y; } \
    else { wo0=__expf(hlo(wO##S)); wo1=__expf(hhi(wO##S)); } \
    S0 = fmaf(S0, wo0, fmaf(saO, bo0, vOf * ko0)); \
    S1 = fmaf(S1, wo1, fmaf(saO, bo1, vOf * ko1)); \
    if (l31 == 0){ \
      Y[rowb + (size_t)(T_) * CC]     = f2bf(ypE); \
      Y[rowb + (size_t)(T_ + 1) * CC] = f2bf(ypO); \
    } \
  }while(0)

  PL(A, 0); PL(B, 2); PL(C, 4); PL(D, 6);
  for (int t = 0; t < TT; t += 8){
    PSTEP(A, t);
    if (t + 8  < TT) PL(A, t + 8);
    PSTEP(B, t + 2);
    if (t + 10 < TT) PL(B, t + 10);
    PSTEP(C, t + 4);
    if (t + 12 < TT) PL(C, t + 12);
    PSTEP(D, t + 6);
    if (t + 14 < TT) PL(D, t + 14);
  }
#undef PL
#undef PSTEP
}

// ---------------------------------------------------------------------------
// Post: GroupNorm + precomputed bonus rk*v + precomputed gate GV -> YG (bf16)
// ---------------------------------------------------------------------------
__global__ __launch_bounds__(256) void k_post(const bf16u* __restrict__ Y,
                                              const bf16u* __restrict__ Vt,
                                              const bf16u* __restrict__ GV,
                                              const float* __restrict__ lnw,
                                              const float* __restrict__ lnb,
                                              const float* __restrict__ RKsc,
                                              bf16u* __restrict__ YG){
  int n = blockIdx.x, tid = threadIdx.x;
  int c = tid * 4;
  size_t e = (size_t)n * CC + c;

  float ya[4]; ld4bf(Y + e, ya);
  float s = ya[0] + ya[1] + ya[2] + ya[3];
  s = red16(s);
  float mu = s * (1.f / 64.f);
  float d[4], vs = 0.f;
  #pragma unroll
  for (int i = 0; i < 4; ++i){ d[i] = ya[i] - mu; vs += d[i] * d[i]; }
  vs = red16(vs);
  float rstd = rsqrtf(vs * (1.f / 64.f) + EPSGN);

  float rk = RKsc[(size_t)n * HH + (tid >> 4)];

  float va[4]; ld4bf(Vt + e, va);
  float lw4[4], lb4[4];
  ld4f(lnw + c, lw4); ld4f(lnb + c, lb4);
  float g[4]; ld4bf(GV + e, g);
  float o[4];
  #pragma unroll
  for (int i = 0; i < 4; ++i){
    float yn = d[i] * rstd * lw4[i] + lb4[i] + rk * va[i];
    o[i] = yn * g[i];
  }
  st4bf(YG + e, o);
}

// ---------------------------------------------------------------------------
extern "C" void kernel_launch(void* const* d_in, const int* in_sizes, int n_in,
                              void* d_out, int out_size, void* d_ws, size_t ws_size,
                              hipStream_t stream){
  (void)in_sizes; (void)n_in; (void)out_size;
  const float* x        = (const float*)d_in[0];
  const float* tmx      = (const float*)d_in[1];
  const float* tmaa     = (const float*)d_in[2];
  const float* maa_w1   = (const float*)d_in[3];
  const float* maa_w2   = (const float*)d_in[4];
  const float* decay_w1 = (const float*)d_in[5];
  const float* decay_w2 = (const float*)d_in[6];
  const float* aaa_w1   = (const float*)d_in[7];
  const float* aaa_w2   = (const float*)d_in[8];
  const float* kkk_w1   = (const float*)d_in[9];
  const float* kkk_w2   = (const float*)d_in[10];
  const float* gate_w1  = (const float*)d_in[11];
  const float* gate_w2  = (const float*)d_in[12];
  const float* ma_w1    = (const float*)d_in[13];
  const float* ma_w2    = (const float*)d_in[14];
  const float* mk_w1    = (const float*)d_in[15];
  const float* mk_w2    = (const float*)d_in[16];
  const float* t_decay  = (const float*)d_in[17];
  const float* t_faaaa  = (const float*)d_in[18];
  const float* t_aaaaa  = (const float*)d_in[19];
  const float* t_misc_a = (const float*)d_in[20];
  const float* t_misc_k = (const float*)d_in[21];
  const float* Wr       = (const float*)d_in[22];
  const float* Wk       = (const float*)d_in[23];
  const float* Wv       = (const float*)d_in[24];
  const float* Wo       = (const float*)d_in[25];
  const float* ln_w     = (const float*)d_in[26];
  const float* ln_b     = (const float*)d_in[27];

  // Slot map (8MiB bf16 each), 56 MiB slots + smalls at 56..60 MiB.
  // 60..76 MiB region time-shared: phase A (weights) -> phase B (WF).
  // Fast path r13: WoB/GW2T live in S2 (UX slot, dead when WMODE=1).
  bf16u* bw  = (bf16u*)d_ws;
  bf16u* MIX = bw + 0*SLOT;
  bf16u* X0  = bw + 0*SLOT;
  bf16u* KKN = bw + 0*SLOT;
  bf16u* YG  = bw + 0*SLOT;
  bf16u* X1  = bw + 1*SLOT;
  bf16u* Bb  = bw + 1*SLOT;
  bf16u* GV  = bw + 1*SLOT;
  bf16u* X2  = bw + 2*SLOT;
  bf16u* UX  = bw + 2*SLOT;
  bf16u* X3  = bw + 3*SLOT;
  bf16u* W2A = bw + 3*SLOT;
  bf16u* Yb  = bw + 3*SLOT;
  bf16u* R   = bw + 4*SLOT;   // becomes q'
  bf16u* K0  = bw + 5*SLOT;   // becomes KF
  bf16u* V   = bw + 6*SLOT;
  char*  wsb = (char*)d_ws;
  bf16u* LO  = (bf16u*)(wsb + (56ull<<20));   // [N,128] bf16, 1 MiB
  bf16u* GT  = (bf16u*)(wsb + (57ull<<20));   // [N,128] bf16, 1 MiB
  bf16u* P1  = (bf16u*)(wsb + (58ull<<20));   // [N,96]  bf16 (dt|at|ma)
  bf16u* P2  = (bf16u*)(wsb + (58ull<<20) + (768ull<<10)); // [N,32] bf16
  float* Dsc = (float*)(wsb + (59ull<<20));   // [N/2,16] float4, 512 KiB
  float* RKsc= (float*)(wsb + (59ull<<20) + (512ull<<10)); // [N,16] f32, 256 KiB
  float* WF  = (float*)(wsb + (60ull<<20));   // [N,CC] f32 w_t, 16 MiB
  bf16u* WrB = (bf16u*)(wsb + (60ull<<20));
  bf16u* WkB = (bf16u*)(wsb + (62ull<<20));
  bf16u* WvB = (bf16u*)(wsb + (64ull<<20));
  bf16u* W1B = (bf16u*)(wsb + (66ull<<20));   // 384 rows x 1024, 0.75 MiB
  bf16u* W2TB= (bf16u*)(wsb + (67ull<<20));   // [1024][192], 0.375 MiB
  bf16u* WoB = UX;                            // S2 (dead in fast path), 2 MiB
  bf16u* GW2T= UX + 1048576;                  // S2 + 2 MiB: [1024][128] bf16
  const bool fast = ws_size >= (77ull<<20);

  if (fast){
    // 0. weight pre-conversion (bf16; identical RNE rounding)
    k_wconv1<<<3648, 256, 0, stream>>>(Wr, Wk, Wv, maa_w1, gate_w1, decay_w1,
                                       aaa_w1, ma_w1, kkk_w1, mk_w1,
                                       maa_w2, decay_w2,
                                       WrB, WkB, WvB, W1B, W2TB);
    // 2. lo = tanh(mix @ maa_w1^T) with mix fused into A-staging
    k_gemm_b64_mix<<<dim3(1,64),256,0,stream>>>(x, tmx, W1B, LO, 128, 128);
    // 3. xm[g]: 4 NN-GEMMs merged into one launch (grid.z = group)
    k_gemm_nn_b4<<<dim3(8,32,4),256,0,stream>>>(LO, W2TB, X0, x, tmaa);
    // 4. big projections merged (z=3, 1536 blocks, BK=64 pipelined)
    k_gemm_b64_rkv<<<dim3(8,64,3),256,0,stream>>>(X0, X2, X3, WrB, WkB, WvB,
                                                  R, K0, V);
    // 5. LoRA projections merged into one launch (grid.z = which)
    k_gemm_b64_lora<<<dim3(1,64,3),256,0,stream>>>(X0, X1, X2, W1B, GT, P1, P2);
    // 6. W2A = P1[:, :64] @ decay_w2 (last read of W2TB before WF overwrites)
    k_gemm_nn_b<64,0><<<dim3(8,32),256,0,stream>>>(P1, 96, W2TB, 128, W2A, nullptr, nullptr);
    // 7. fused elementwise + pair precompute + Wo/gate_w2 conversion
    k_elem<1><<<2560, 256, 0, stream>>>(K0, P1, P2, W2A,
                                        kkk_w2, aaa_w2, ma_w2, mk_w2,
                                        t_decay, t_aaaaa, t_misc_a, t_misc_k, t_faaaa,
                                        KKN, Bb, UX, WF, R, Dsc, RKsc,
                                        Wo, gate_w2, WoB, GW2T);
    // 8. delta-rule recurrence (r8-validated v13)
    k_rec<1><<<512, 256, 0, stream>>>(R, UX, WF, K0, V, KKN, Bb, Dsc, Yb);
    // 9. GV = GT @ gate_w2 (BK=64 fast NT path; GW2T from step 7)
    k_gemm_b64<true><<<dim3(8,64),256,0,stream>>>(GT, GW2T, GV, CC, 128, 0);
    // 10. groupnorm + bonus + gate
    k_post<<<4096, 256, 0, stream>>>(Yb, V, GV, ln_w, ln_b, RKsc, YG);
    // 11. out = yg @ Wo^T -> f32 (WoB from step 7, lives in S2)
    k_gemm_b64<false><<<dim3(8,64),256,0,stream>>>(YG, WoB, d_out, CC, CC, 0);
  } else {
    // Fallback: exact r8 sequence (f32 weights in-GEMM, f16 -u decay).
    k_prep<<<4096, 256, 0, stream>>>(x, tmx, MIX);
    k_gemm_mfma<true><<<dim3(1,32),256,0,stream>>>(MIX, maa_w1, maa_w1, maa_w1,
                                                   128, 128, LO, 128, CC, 128);
    bf16u* XMs[4] = {X0, X1, X2, X3};
    for (int g = 0; g < 4; ++g)
      k_gemm_nn<32,1><<<dim3(8,32),256,0,stream>>>(LO + g*32, 128,
                                                   maa_w2 + (size_t)g*32*CC,
                                                   XMs[g], x, tmaa + (size_t)g*CC);
    k_gemm_mfma<true><<<dim3(8,32),256,0,stream>>>(X0, Wr, Wr, Wr, CC, CC, R,  CC, CC, 0);
    k_gemm_mfma<true><<<dim3(8,32),256,0,stream>>>(X2, Wk, Wk, Wk, CC, CC, K0, CC, CC, 0);
    k_gemm_mfma<true><<<dim3(8,32),256,0,stream>>>(X3, Wv, Wv, Wv, CC, CC, V,  CC, CC, 0);
    k_gemm_mfma<true><<<dim3(1,32),256,0,stream>>>(X0, gate_w1, gate_w1, gate_w1,
                                                   128, 128, GT, 128, CC, 128);
    k_gemm_mfma<true><<<dim3(1,32),256,0,stream>>>(X1, decay_w1, aaa_w1, ma_w1,
                                                   64, 80, P1, 96, CC, 64);
    k_gemm_mfma<true><<<dim3(1,32),256,0,stream>>>(X2, kkk_w1, mk_w1, mk_w1,
                                                   16, 32, P2, 32, CC, 16);
    k_gemm_nn<64,0><<<dim3(8,32),256,0,stream>>>(P1, 96, decay_w2, W2A, nullptr, nullptr);
    k_elem<0><<<1024, 256, 0, stream>>>(K0, P1, P2, W2A,
                                        kkk_w2, aaa_w2, ma_w2, mk_w2,
                                        t_decay, t_aaaaa, t_misc_a, t_misc_k, t_faaaa,
                                        KKN, Bb, UX, WF, R, Dsc, RKsc,
                                        Wo, gate_w2, WoB, GW2T);
    k_rec<0><<<512, 256, 0, stream>>>(R, UX, WF, K0, V, KKN, Bb, Dsc, Yb);
    k_gemm_nn<128,0><<<dim3(8,32),256,0,stream>>>(GT, 128, gate_w2, GV, nullptr, nullptr);
    k_post<<<4096, 256, 0, stream>>>(Yb, V, GV, ln_w, ln_b, RKsc, YG);
    k_gemm_mfma<false><<<dim3(8,32),256,0,stream>>>(YG, Wo, Wo, Wo, CC, CC, d_out, CC, CC, 0);
  }
}

// Round 14
// 567.215 us; speedup vs baseline: 1.3461x; 1.3461x over previous
//
#include <hip/hip_runtime.h>
#include <cstdint>
#include <cstddef>

// Problem constants
#define BB   4
#define TT   1024
#define CC   1024
#define HH   16
#define HSS  64
#define NNtok 4096            // B*T
#define EPSGN 0.00064f
#define W2TS 192              // W2TB col count (maa_w2 128 | decay_w2 64)

typedef unsigned short bf16u;
typedef __attribute__((ext_vector_type(8))) short short8;
typedef __attribute__((ext_vector_type(4))) float f32x4;
#define SLOT 4194304ull       // elements per 8MiB bf16 slot (= NNtok*CC)

__device__ __forceinline__ float bf2f(bf16u u){
  union { unsigned int i; float f; } cv; cv.i = ((unsigned int)u) << 16; return cv.f;
}
__device__ __forceinline__ unsigned short f2bfbits(unsigned int x){
  return (unsigned short)((x + 0x7fffu + ((x >> 16) & 1u)) >> 16);   // RNE
}
__device__ __forceinline__ bf16u f2bf(float f){
  union { float f; unsigned int i; } cv; cv.f = f;
  return f2bfbits(cv.i);
}
__device__ __forceinline__ void ld4bf(const bf16u* p, float* o){
  ushort4 u = *reinterpret_cast<const ushort4*>(p);
  o[0]=bf2f(u.x); o[1]=bf2f(u.y); o[2]=bf2f(u.z); o[3]=bf2f(u.w);
}
__device__ __forceinline__ void st4bf(bf16u* p, const float* v){
  ushort4 u; u.x=f2bf(v[0]); u.y=f2bf(v[1]); u.z=f2bf(v[2]); u.w=f2bf(v[3]);
  *reinterpret_cast<ushort4*>(p) = u;
}
__device__ __forceinline__ unsigned short f2h(float f){
  union { _Float16 h; unsigned short s; } c; c.h = (_Float16)f; return c.s;
}
__device__ __forceinline__ void st4h(bf16u* p, const float* v){
  ushort4 u; u.x=f2h(v[0]); u.y=f2h(v[1]); u.z=f2h(v[2]); u.w=f2h(v[3]);
  *reinterpret_cast<ushort4*>(p) = u;
}
__device__ __forceinline__ void ld4f(const float* p, float* o){
  float4 v = *reinterpret_cast<const float4*>(p);
  o[0]=v.x; o[1]=v.y; o[2]=v.z; o[3]=v.w;
}
__device__ __forceinline__ float sigm(float x){ return 1.f / (1.f + expf(-x)); }

// unpack helpers
__device__ __forceinline__ float bflo(unsigned int u){
  union { unsigned int i; float f; } c; c.i = u << 16; return c.f;
}
__device__ __forceinline__ float bfhi(unsigned int u){
  union { unsigned int i; float f; } c; c.i = u & 0xffff0000u; return c.f;
}
__device__ __forceinline__ float hlo(unsigned int u){
  union { unsigned short s; _Float16 h; } c; c.s = (unsigned short)(u & 0xffffu); return (float)c.h;
}
__device__ __forceinline__ float hhi(unsigned int u){
  union { unsigned short s; _Float16 h; } c; c.s = (unsigned short)(u >> 16); return (float)c.h;
}
__device__ __forceinline__ float hval(unsigned short s){
  union { unsigned short s; _Float16 h; } c; c.s = s; return (float)c.h;
}
__device__ __forceinline__ float dot4(const float* x, const float* y){
  return (x[0]*y[0] + x[1]*y[1]) + (x[2]*y[2] + x[3]*y[3]);
}

// 16-lane sum via DPP. old=0 + bound_ctrl=1 folds to single v_add_f32_dpp.
template<int CTRL>
__device__ __forceinline__ float dpp_add(float v){
  union { float f; int i; } a, b;
  a.f = v;
  b.i = __builtin_amdgcn_update_dpp(0, a.i, CTRL, 0xF, 0xF, true);
  return v + b.f;
}
__device__ __forceinline__ float red16(float v){
  v = dpp_add<0xB1>(v);    // quad_perm [1,0,3,2]  (xor 1)
  v = dpp_add<0x4E>(v);    // quad_perm [2,3,0,1]  (xor 2)
  v = dpp_add<0x124>(v);   // row_ror:4
  v = dpp_add<0x128>(v);   // row_ror:8
  return v;
}
// 32-lane sum in all lanes: red16 then exchange complementary 16-rows
// between two DISTINCT-register copies (laundered; rounds 1/3 failed when
// regalloc coalesced both operands into one phys reg -> self-swap).
__device__ __forceinline__ float red32(float v){
  v = red16(v);
  union { float f; int i; } x, y;
  x.f = v; y.f = v;
  asm volatile("" : "+v"(y.i));   // distinct-vreg launder
  asm volatile("v_permlane16_swap_b32 %0, %1" : "+v"(x.i), "+v"(y.i));
  return x.f + y.f;
}

// ---------------------------------------------------------------------------
// mix = x + (x[t-1]-x[t])*time_maa_x  (x[-1]=0), stored bf16 (fallback path)
// ---------------------------------------------------------------------------
__global__ __launch_bounds__(256) void k_prep(const float* __restrict__ x,
                                              const float* __restrict__ tmx,
                                              bf16u* __restrict__ MIX){
  int e = (blockIdx.x * 256 + threadIdx.x) * 4;
  int n = e >> 10;
  int c = e & (CC - 1);
  int t = n & (TT - 1);
  float xf[4]; ld4f(x + e, xf);
  float pf[4] = {0.f, 0.f, 0.f, 0.f};
  if (t > 0) ld4f(x + e - CC, pf);
  float tm[4]; ld4f(tmx + c, tm);
  float mv[4];
  #pragma unroll
  for (int i = 0; i < 4; ++i) mv[i] = xf[i] + (pf[i] - xf[i]) * tm[i];
  st4bf(MIX + e, mv);
}

// ---------------------------------------------------------------------------
// MERGED prep + weight pre-conversion (r12 structure, restored after r13's
// mix-fusion regression: mix work needs full-device concurrency, not a
// 64-block GEMM's prefetch path). blk<4096: mix; else: weight convert.
// ---------------------------------------------------------------------------
__global__ __launch_bounds__(256) void k_prep_wconv(
    const float* __restrict__ x, const float* __restrict__ tmx,
    bf16u* __restrict__ MIX,
    const float* __restrict__ Wr, const float* __restrict__ Wk,
    const float* __restrict__ Wv,
    const float* __restrict__ maa_w1, const float* __restrict__ gate_w1,
    const float* __restrict__ decay_w1, const float* __restrict__ aaa_w1,
    const float* __restrict__ ma_w1, const float* __restrict__ kkk_w1,
    const float* __restrict__ mk_w1,
    const float* __restrict__ maa_w2, const float* __restrict__ decay_w2,
    bf16u* __restrict__ WrB, bf16u* __restrict__ WkB, bf16u* __restrict__ WvB,
    bf16u* __restrict__ W1B, bf16u* __restrict__ W2TB){
  int tid = threadIdx.x;
  if (blockIdx.x < 4096){
    int e = (blockIdx.x * 256 + tid) * 4;
    int n = e >> 10;
    int c = e & (CC - 1);
    int t = n & (TT - 1);
    float xf[4]; ld4f(x + e, xf);
    float pf[4] = {0.f, 0.f, 0.f, 0.f};
    if (t > 0) ld4f(x + e - CC, pf);
    float tm[4]; ld4f(tmx + c, tm);
    float mv[4];
    #pragma unroll
    for (int i = 0; i < 4; ++i) mv[i] = xf[i] + (pf[i] - xf[i]) * tm[i];
    st4bf(MIX + e, mv);
    return;
  }
  int blk = blockIdx.x - 4096;
  if (blk < 3072){
    const float* src = (blk < 1024) ? Wr : (blk < 2048) ? Wk : Wv;
    bf16u* dst = (blk < 1024) ? WrB : (blk < 2048) ? WkB : WvB;
    size_t e = (size_t)(blk & 1023) * 1024 + (size_t)tid * 4;
    float v[4]; ld4f(src + e, v);
    st4bf(dst + e, v);
  } else if (blk < 3456){
    int row = blk - 3072;
    const float* src;
    if      (row < 128) src = maa_w1   + (size_t)row * 1024;
    else if (row < 256) src = gate_w1  + (size_t)(row - 128) * 1024;
    else if (row < 320) src = decay_w1 + (size_t)(row - 256) * 1024;
    else if (row < 336) src = aaa_w1   + (size_t)(row - 320) * 1024;
    else if (row < 352) src = ma_w1    + (size_t)(row - 336) * 1024;
    else if (row < 368) src = kkk_w1   + (size_t)(row - 352) * 1024;
    else                src = mk_w1    + (size_t)(row - 368) * 1024;
    float v[4]; ld4f(src + tid * 4, v);
    st4bf(W1B + (size_t)row * 1024 + tid * 4, v);
  } else {
    int j = blk - 3456;   // 0..191
    const float* src = (j < 128) ? (maa_w2 + (size_t)j * 1024)
                                 : (decay_w2 + (size_t)(j - 128) * 1024);
    for (int c = tid; c < 1024; c += 256)
      W2TB[(size_t)c * W2TS + j] = f2bf(src[c]);
  }
}

// ---------------------------------------------------------------------------
// MFMA NT GEMM body, bf16-W, M64xN128, BK=64 double-K staging.
// ---------------------------------------------------------------------------
#define B64_AROW 72
#define B64_ASZ (64*72)
#define B64_BSZ (128*72)
template<bool OB>
__device__ __forceinline__ void gemm_b64_body(const bf16u* __restrict__ X,
                                              const bf16u* __restrict__ WB,
                                              void* __restrict__ OUTv,
                                              int Nd, int Kd, int act_n,
                                              short* __restrict__ As,
                                              short* __restrict__ Bs,
                                              int bn0, int bm0){
  const int tid  = threadIdx.x;
  const int lane = tid & 63;
  const int wv   = tid >> 6;
  const int wm   = wv >> 1, wn = wv & 1;   // wave -> 32-row x 64-col subtile
  const int l15  = lane & 15;
  const int quad = lane >> 4;

  f32x4 acc[2][4];
  #pragma unroll
  for (int mi = 0; mi < 2; ++mi)
    #pragma unroll
    for (int ni = 0; ni < 4; ++ni)
      #pragma unroll
      for (int rg = 0; rg < 4; ++rg) acc[mi][ni][rg] = 0.f;

  const int ra = tid >> 2, k0a = (tid & 3) * 16;   // A: 64 rows x 64k, 2 uint4/thr
  const int rb = tid >> 1, k0b = (tid & 1) * 32;   // B: 128 rows x 64k, 4 uint4/thr
  const bf16u* xsrc = X + (size_t)(bm0 + ra) * Kd;
  const bf16u* wsrc = (bn0 + rb < Nd) ? WB + (size_t)(bn0 + rb) * Kd : nullptr;

  uint4 xa0 = *(const uint4*)(xsrc + k0a);
  uint4 xa1 = *(const uint4*)(xsrc + k0a + 8);
  uint4 wa0 = make_uint4(0,0,0,0), wa1 = wa0, wa2 = wa0, wa3 = wa0;
  if (wsrc){
    wa0 = *(const uint4*)(wsrc + k0b);
    wa1 = *(const uint4*)(wsrc + k0b + 8);
    wa2 = *(const uint4*)(wsrc + k0b + 16);
    wa3 = *(const uint4*)(wsrc + k0b + 24);
  }
  *(uint4*)&As[ra * B64_AROW + k0a]      = xa0;
  *(uint4*)&As[ra * B64_AROW + k0a + 8]  = xa1;
  *(uint4*)&Bs[rb * B64_AROW + k0b]      = wa0;
  *(uint4*)&Bs[rb * B64_AROW + k0b + 8]  = wa1;
  *(uint4*)&Bs[rb * B64_AROW + k0b + 16] = wa2;
  *(uint4*)&Bs[rb * B64_AROW + k0b + 24] = wa3;
  __syncthreads();

  const int NS = Kd >> 6;
  for (int s = 0; s < NS; ++s){
    const int cur = s & 1;
    if (s + 1 < NS){                    // issue next-stage loads BEFORE compute
      int kb = (s + 1) << 6;
      xa0 = *(const uint4*)(xsrc + kb + k0a);
      xa1 = *(const uint4*)(xsrc + kb + k0a + 8);
      if (wsrc){
        wa0 = *(const uint4*)(wsrc + kb + k0b);
        wa1 = *(const uint4*)(wsrc + kb + k0b + 8);
        wa2 = *(const uint4*)(wsrc + kb + k0b + 16);
        wa3 = *(const uint4*)(wsrc + kb + k0b + 24);
      }
    }
    #pragma unroll
    for (int kk = 0; kk < 64; kk += 32){
      short8 af[2], bfg[4];
      #pragma unroll
      for (int mi = 0; mi < 2; ++mi)
        af[mi] = *(const short8*)&As[cur*B64_ASZ + (wm*32 + mi*16 + l15) * B64_AROW + kk + quad*8];
      #pragma unroll
      for (int ni = 0; ni < 4; ++ni)
        bfg[ni] = *(const short8*)&Bs[cur*B64_BSZ + (wn*64 + ni*16 + l15) * B64_AROW + kk + quad*8];
      #pragma unroll
      for (int mi = 0; mi < 2; ++mi)
        #pragma unroll
        for (int ni = 0; ni < 4; ++ni)
          acc[mi][ni] = __builtin_amdgcn_mfma_f32_16x16x32_bf16(af[mi], bfg[ni], acc[mi][ni], 0, 0, 0);
    }
    if (s + 1 < NS){
      const int nxt = cur ^ 1;
      *(uint4*)&As[nxt*B64_ASZ + ra * B64_AROW + k0a]      = xa0;
      *(uint4*)&As[nxt*B64_ASZ + ra * B64_AROW + k0a + 8]  = xa1;
      *(uint4*)&Bs[nxt*B64_BSZ + rb * B64_AROW + k0b]      = wa0;
      *(uint4*)&Bs[nxt*B64_BSZ + rb * B64_AROW + k0b + 8]  = wa1;
      *(uint4*)&Bs[nxt*B64_BSZ + rb * B64_AROW + k0b + 16] = wa2;
      *(uint4*)&Bs[nxt*B64_BSZ + rb * B64_AROW + k0b + 24] = wa3;
      __syncthreads();
    }
  }

  #pragma unroll
  for (int mi = 0; mi < 2; ++mi){
    #pragma unroll
    for (int ni = 0; ni < 4; ++ni){
      int col = bn0 + wn*64 + ni*16 + l15;
      if (col >= Nd) continue;
      #pragma unroll
      for (int rg = 0; rg < 4; ++rg){
        int row = bm0 + wm*32 + mi*16 + quad*4 + rg;
        float v = acc[mi][ni][rg];
        if (col < act_n) v = tanhf(v);
        if (OB) ((bf16u*)OUTv)[(size_t)row * Nd + col] = f2bf(v);
        else    ((float*)OUTv)[(size_t)row * Nd + col] = v;
      }
    }
  }
}

template<bool OB>
__global__ __launch_bounds__(256) void k_gemm_b64(const bf16u* __restrict__ X,
                                                  const bf16u* __restrict__ WB,
                                                  void* __restrict__ OUTv,
                                                  int Nd, int Kd, int act_n){
  __shared__ short As[2*B64_ASZ];
  __shared__ short Bs[2*B64_BSZ];
  gemm_b64_body<OB>(X, WB, OUTv, Nd, Kd, act_n, As, Bs,
                    blockIdx.x * 128, blockIdx.y * 64);
}

// R/K/V big projections merged into one z=3 launch.
__global__ __launch_bounds__(256) void k_gemm_b64_rkv(const bf16u* __restrict__ X0,
                                                      const bf16u* __restrict__ X2,
                                                      const bf16u* __restrict__ X3,
                                                      const bf16u* __restrict__ WrB,
                                                      const bf16u* __restrict__ WkB,
                                                      const bf16u* __restrict__ WvB,
                                                      bf16u* __restrict__ R,
                                                      bf16u* __restrict__ K0,
                                                      bf16u* __restrict__ V){
  __shared__ short As[2*B64_ASZ];
  __shared__ short Bs[2*B64_BSZ];
  const int z = blockIdx.z;
  const int bn0 = blockIdx.x * 128, bm0 = blockIdx.y * 64;
  if (z == 0)      gemm_b64_body<true>(X0, WrB, R,  CC, CC, 0, As, Bs, bn0, bm0);
  else if (z == 1) gemm_b64_body<true>(X2, WkB, K0, CC, CC, 0, As, Bs, bn0, bm0);
  else             gemm_b64_body<true>(X3, WvB, V,  CC, CC, 0, As, Bs, bn0, bm0);
}

// 3 LoRA projections merged into one launch (z decodes).
__global__ __launch_bounds__(256) void k_gemm_b64_lora(const bf16u* __restrict__ X0,
                                                       const bf16u* __restrict__ X1,
                                                       const bf16u* __restrict__ X2,
                                                       const bf16u* __restrict__ W1B,
                                                       bf16u* __restrict__ GT,
                                                       bf16u* __restrict__ P1,
                                                       bf16u* __restrict__ P2){
  __shared__ short As[2*B64_ASZ];
  __shared__ short Bs[2*B64_BSZ];
  const int z = blockIdx.z;
  const int bm0 = blockIdx.y * 64;
  if (z == 0)
    gemm_b64_body<true>(X0, W1B + 128*1024, GT, 128, CC, 128, As, Bs, 0, bm0);
  else if (z == 1)
    gemm_b64_body<true>(X1, W1B + 256*1024, P1, 96, CC, 64, As, Bs, 0, bm0);
  else
    gemm_b64_body<true>(X2, W1B + 352*1024, P2, 32, CC, 16, As, Bs, 0, bm0);
}

// ---------------------------------------------------------------------------
// MFMA NN GEMM body, pre-transposed bf16 B (single-staging; K fits in LDS).
// ---------------------------------------------------------------------------
template<int KD, int EP>
__device__ __forceinline__ void gemm_nn_body(const bf16u* __restrict__ A, int lda,
                                             const bf16u* __restrict__ BT, int koff,
                                             bf16u* __restrict__ OUT,
                                             const float* __restrict__ x,
                                             const float* __restrict__ tma_g,
                                             short* __restrict__ As,
                                             short* __restrict__ Bs,
                                             int bn0, int bm0){
  const int tid  = threadIdx.x;
  const int lane = tid & 63;
  const int wv   = tid >> 6;
  const int wm   = wv >> 1, wn = wv & 1;
  const int l15  = lane & 15;
  const int quad = lane >> 4;

  for (int idx = tid; idx < 128 * (KD / 8); idx += 256){
    int r  = idx / (KD / 8);
    int kc = (idx % (KD / 8)) * 8;
    *(uint4*)&As[r * (KD + 8) + kc] =
        *(const uint4*)(A + (size_t)(bm0 + r) * lda + kc);
  }
  for (int idx = tid; idx < 128 * (KD / 8); idx += 256){
    int cc_ = idx / (KD / 8);
    int kc  = (idx % (KD / 8)) * 8;
    *(uint4*)&Bs[cc_ * (KD + 8) + kc] =
        *(const uint4*)(BT + (size_t)(bn0 + cc_) * W2TS + koff + kc);
  }
  __syncthreads();

  f32x4 acc[4][4];
  #pragma unroll
  for (int mi = 0; mi < 4; ++mi)
    #pragma unroll
    for (int ni = 0; ni < 4; ++ni)
      #pragma unroll
      for (int rg = 0; rg < 4; ++rg) acc[mi][ni][rg] = 0.f;

  #pragma unroll
  for (int kk = 0; kk < KD; kk += 32){
    short8 af[4], bfg[4];
    #pragma unroll
    for (int mi = 0; mi < 4; ++mi)
      af[mi] = *(const short8*)&As[(wm*64 + mi*16 + l15) * (KD + 8) + kk + quad*8];
    #pragma unroll
    for (int ni = 0; ni < 4; ++ni)
      bfg[ni] = *(const short8*)&Bs[(wn*64 + ni*16 + l15) * (KD + 8) + kk + quad*8];
    #pragma unroll
    for (int mi = 0; mi < 4; ++mi)
      #pragma unroll
      for (int ni = 0; ni < 4; ++ni)
        acc[mi][ni] = __builtin_amdgcn_mfma_f32_16x16x32_bf16(af[mi], bfg[ni], acc[mi][ni], 0, 0, 0);
  }

  #pragma unroll
  for (int mi = 0; mi < 4; ++mi){
    #pragma unroll
    for (int ni = 0; ni < 4; ++ni){
      int col = bn0 + wn*64 + ni*16 + l15;
      float tm = (EP == 1) ? tma_g[col] : 0.f;
      #pragma unroll
      for (int rg = 0; rg < 4; ++rg){
        int row = bm0 + wm*64 + mi*16 + quad*4 + rg;
        float v = acc[mi][ni][rg];
        if (EP == 1){
          float xv = x[(size_t)row * CC + col];
          float xp = ((row & (TT - 1)) == 0) ? 0.f : x[(size_t)row * CC + col - CC];
          v = xv + (xp - xv) * (v + tm);
        }
        OUT[(size_t)row * CC + col] = f2bf(v);
      }
    }
  }
}

template<int KD, int EP>
__global__ __launch_bounds__(256) void k_gemm_nn_b(const bf16u* __restrict__ A, int lda,
                                                   const bf16u* __restrict__ BT, int koff,
                                                   bf16u* __restrict__ OUT,
                                                   const float* __restrict__ x,
                                                   const float* __restrict__ tma_g){
  __shared__ short As[128 * (KD + 8)];
  __shared__ short Bs[128 * (KD + 8)];
  gemm_nn_body<KD, EP>(A, lda, BT, koff, OUT, x, tma_g, As, Bs,
                       blockIdx.x * 128, blockIdx.y * 128);
}

// 4 xm NN-GEMMs merged into one launch (z = group).
__global__ __launch_bounds__(256) void k_gemm_nn_b4(const bf16u* __restrict__ LO,
                                                    const bf16u* __restrict__ BT,
                                                    bf16u* __restrict__ X0base,
                                                    const float* __restrict__ x,
                                                    const float* __restrict__ tmaa){
  __shared__ short As[128 * 40];
  __shared__ short Bs[128 * 40];
  const int z = blockIdx.z;
  gemm_nn_body<32, 1>(LO + z*32, 128, BT, z*32, X0base + (size_t)z*SLOT,
                      x, tmaa + (size_t)z*CC, As, Bs,
                      blockIdx.x * 128, blockIdx.y * 128);
}

// ---------------------------------------------------------------------------
// LEGACY f32-W GEMMs (fallback path only)
// ---------------------------------------------------------------------------
template<bool OB>
__global__ __launch_bounds__(256) void k_gemm_mfma(const bf16u* __restrict__ X,
                                                   const float* __restrict__ Wa,
                                                   const float* __restrict__ Wb,
                                                   const float* __restrict__ Wc,
                                                   int na, int nab,
                                                   void* __restrict__ OUTv,
                                                   int Nd, int Kd, int act_n){
  __shared__ short As[128 * 40];
  __shared__ short Bs[128 * 40];
  const int tid  = threadIdx.x;
  const int lane = tid & 63;
  const int wv   = tid >> 6;
  const int wm   = wv >> 1, wn = wv & 1;
  const int bn0  = blockIdx.x * 128;
  const int bm0  = blockIdx.y * 128;
  const int l15  = lane & 15;
  const int quad = lane >> 4;

  f32x4 acc[4][4];
  #pragma unroll
  for (int mi = 0; mi < 4; ++mi)
    #pragma unroll
    for (int ni = 0; ni < 4; ++ni)
      #pragma unroll
      for (int rg = 0; rg < 4; ++rg) acc[mi][ni][rg] = 0.f;

  const int r    = tid >> 1;
  const int half = (tid & 1) * 16;

  int rr = bn0 + r;
  const float* wsrc = nullptr;
  if (rr < na)        wsrc = Wa + (size_t)rr * Kd;
  else if (rr < nab)  wsrc = Wb + (size_t)(rr - na) * Kd;
  else if (rr < Nd)   wsrc = Wc + (size_t)(rr - nab) * Kd;
  const bf16u* xsrc = X + (size_t)(bm0 + r) * Kd;

  for (int k0 = 0; k0 < Kd; k0 += 32){
    uint4 xa = *(const uint4*)(xsrc + k0 + half);
    uint4 xb = *(const uint4*)(xsrc + k0 + half + 8);
    uint4 w0 = make_uint4(0,0,0,0), w1 = w0, w2 = w0, w3 = w0;
    if (wsrc){
      w0 = *(const uint4*)(wsrc + k0 + half);
      w1 = *(const uint4*)(wsrc + k0 + half + 4);
      w2 = *(const uint4*)(wsrc + k0 + half + 8);
      w3 = *(const uint4*)(wsrc + k0 + half + 12);
    }
    union { unsigned short s[8]; uint4 v; } p0, p1;
    p0.s[0]=f2bfbits(w0.x); p0.s[1]=f2bfbits(w0.y); p0.s[2]=f2bfbits(w0.z); p0.s[3]=f2bfbits(w0.w);
    p0.s[4]=f2bfbits(w1.x); p0.s[5]=f2bfbits(w1.y); p0.s[6]=f2bfbits(w1.z); p0.s[7]=f2bfbits(w1.w);
    p1.s[0]=f2bfbits(w2.x); p1.s[1]=f2bfbits(w2.y); p1.s[2]=f2bfbits(w2.z); p1.s[3]=f2bfbits(w2.w);
    p1.s[4]=f2bfbits(w3.x); p1.s[5]=f2bfbits(w3.y); p1.s[6]=f2bfbits(w3.z); p1.s[7]=f2bfbits(w3.w);

    *(uint4*)&As[r * 40 + half]     = xa;
    *(uint4*)&As[r * 40 + half + 8] = xb;
    *(uint4*)&Bs[r * 40 + half]     = p0.v;
    *(uint4*)&Bs[r * 40 + half + 8] = p1.v;
    __syncthreads();

    short8 af[4], bfg[4];
    #pragma unroll
    for (int mi = 0; mi < 4; ++mi)
      af[mi] = *(const short8*)&As[(wm*64 + mi*16 + l15) * 40 + quad*8];
    #pragma unroll
    for (int ni = 0; ni < 4; ++ni)
      bfg[ni] = *(const short8*)&Bs[(wn*64 + ni*16 + l15) * 40 + quad*8];
    #pragma unroll
    for (int mi = 0; mi < 4; ++mi)
      #pragma unroll
      for (int ni = 0; ni < 4; ++ni)
        acc[mi][ni] = __builtin_amdgcn_mfma_f32_16x16x32_bf16(af[mi], bfg[ni], acc[mi][ni], 0, 0, 0);
    __syncthreads();
  }

  #pragma unroll
  for (int mi = 0; mi < 4; ++mi){
    #pragma unroll
    for (int ni = 0; ni < 4; ++ni){
      int col = bn0 + wn*64 + ni*16 + l15;
      if (col >= Nd) continue;
      #pragma unroll
      for (int rg = 0; rg < 4; ++rg){
        int row = bm0 + wm*64 + mi*16 + quad*4 + rg;
        float v = acc[mi][ni][rg];
        if (col < act_n) v = tanhf(v);
        if (OB) ((bf16u*)OUTv)[(size_t)row * Nd + col] = f2bf(v);
        else    ((float*)OUTv)[(size_t)row * Nd + col] = v;
      }
    }
  }
}

template<int KD, int EP>
__global__ __launch_bounds__(256) void k_gemm_nn(const bf16u* __restrict__ A, int lda,
                                                 const float* __restrict__ B,
                                                 bf16u* __restrict__ OUT,
                                                 const float* __restrict__ x,
                                                 const float* __restrict__ tma_g){
  __shared__ short As[128 * (KD + 8)];
  __shared__ short Bs[128 * (KD + 8)];
  const int tid  = threadIdx.x;
  const int lane = tid & 63;
  const int wv   = tid >> 6;
  const int wm   = wv >> 1, wn = wv & 1;
  const int bn0  = blockIdx.x * 128;
  const int bm0  = blockIdx.y * 128;
  const int l15  = lane & 15;
  const int quad = lane >> 4;

  for (int idx = tid; idx < 128 * (KD / 8); idx += 256){
    int r  = idx / (KD / 8);
    int kc = (idx % (KD / 8)) * 8;
    *(uint4*)&As[r * (KD + 8) + kc] =
        *(const uint4*)(A + (size_t)(bm0 + r) * lda + kc);
  }
  for (int idx = tid; idx < KD * 128; idx += 256){
    int k = idx >> 7, c = idx & 127;
    Bs[c * (KD + 8) + k] = (short)f2bf(B[(size_t)k * CC + bn0 + c]);
  }
  __syncthreads();

  f32x4 acc[4][4];
  #pragma unroll
  for (int mi = 0; mi < 4; ++mi)
    #pragma unroll
    for (int ni = 0; ni < 4; ++ni)
      #pragma unroll
      for (int rg = 0; rg < 4; ++rg) acc[mi][ni][rg] = 0.f;

  #pragma unroll
  for (int kk = 0; kk < KD; kk += 32){
    short8 af[4], bfg[4];
    #pragma unroll
    for (int mi = 0; mi < 4; ++mi)
      af[mi] = *(const short8*)&As[(wm*64 + mi*16 + l15) * (KD + 8) + kk + quad*8];
    #pragma unroll
    for (int ni = 0; ni < 4; ++ni)
      bfg[ni] = *(const short8*)&Bs[(wn*64 + ni*16 + l15) * (KD + 8) + kk + quad*8];
    #pragma unroll
    for (int mi = 0; mi < 4; ++mi)
      #pragma unroll
      for (int ni = 0; ni < 4; ++ni)
        acc[mi][ni] = __builtin_amdgcn_mfma_f32_16x16x32_bf16(af[mi], bfg[ni], acc[mi][ni], 0, 0, 0);
  }

  #pragma unroll
  for (int mi = 0; mi < 4; ++mi){
    #pragma unroll
    for (int ni = 0; ni < 4; ++ni){
      int col = bn0 + wn*64 + ni*16 + l15;
      float tm = (EP == 1) ? tma_g[col] : 0.f;
      #pragma unroll
      for (int rg = 0; rg < 4; ++rg){
        int row = bm0 + wm*64 + mi*16 + quad*4 + rg;
        float v = acc[mi][ni][rg];
        if (EP == 1){
          float xv = x[(size_t)row * CC + col];
          float xp = ((row & (TT - 1)) == 0) ? 0.f : x[(size_t)row * CC + col - CC];
          v = xv + (xp - xv) * (v + tm);
        }
        OUT[(size_t)row * CC + col] = f2bf(v);
      }
    }
  }
}

// ---------------------------------------------------------------------------
// Fused elementwise + pair precompute + (fast path) Wo/gate_w2 conversion.
// Blocks >=1024 convert Wo -> WoB (S2) and gate_w2 -> GW2T (S2+2MiB); both
// dead in fast path (UX unused) -> one fewer launch. (Kept from r13 — the
// r13 regression was attributed to the mix-fused lo GEMM, reverted this
// round; this fold's extra blocks early-return and are near-free.)
// WMODE=1: w_t stored exact f32 in WF. WMODE=0: f16 -u fallback (grid 1024).
// ---------------------------------------------------------------------------
template<int WMODE>
__global__ __launch_bounds__(256) void k_elem(bf16u* __restrict__ K0,
    const bf16u* __restrict__ P1, const bf16u* __restrict__ P2,
    const bf16u* __restrict__ W2A,
    const float* __restrict__ kw2, const float* __restrict__ aw2,
    const float* __restrict__ maw2, const float* __restrict__ mkw2,
    const float* __restrict__ td,  const float* __restrict__ taa,
    const float* __restrict__ tma, const float* __restrict__ tmk,
    const float* __restrict__ faaaa,
    bf16u* __restrict__ KKN, bf16u* __restrict__ Bb, bf16u* __restrict__ UX,
    float* __restrict__ WF,
    bf16u* __restrict__ Rq, float* __restrict__ Dsc, float* __restrict__ RKsc,
    const float* __restrict__ Wo, const float* __restrict__ gate_w2,
    bf16u* __restrict__ WoB, bf16u* __restrict__ GW2T){
  int tid = threadIdx.x;
  if (blockIdx.x >= 1024){
    int blk = blockIdx.x - 1024;
    if (blk < 1024){
      size_t e = ((size_t)blk * 256 + tid) * 4;
      float v[4]; ld4f(Wo + e, v);
      st4bf(WoB + e, v);
    } else {
      int c = (blk - 1024) * 2 + (tid >> 7);
      int j = tid & 127;
      GW2T[(size_t)c * 128 + j] = f2bf(gate_w2[(size_t)j * CC + c]);
    }
    return;
  }
  int n0 = blockIdx.x * 4;
  __shared__ float at_l[4][16], mat_l[4][16], kt_l[4][16], mkt_l[4][16];
  {
    int grp = tid >> 6, q = tid & 63, tt = q >> 4, j = q & 15;
    if (grp == 0)      at_l[tt][j]  = bf2f(P1[(size_t)(n0+tt)*96 + 64 + j]);
    else if (grp == 1) mat_l[tt][j] = bf2f(P1[(size_t)(n0+tt)*96 + 80 + j]);
    else if (grp == 2) kt_l[tt][j]  = bf2f(P2[(size_t)(n0+tt)*32 + j]);
    else               mkt_l[tt][j] = bf2f(P2[(size_t)(n0+tt)*32 + 16 + j]);
  }
  __syncthreads();
  int c  = tid * 4;
  int h  = tid >> 4;       // head (16 lanes per head)
  int lg = tid & 15;

  float kkk[4][4], aa[4][4], mam[4][4], mkm[4][4];
  #pragma unroll
  for (int tt = 0; tt < 4; ++tt)
    #pragma unroll
    for (int i = 0; i < 4; ++i){ kkk[tt][i]=0; aa[tt][i]=0; mam[tt][i]=0; mkm[tt][i]=0; }

  #pragma unroll 4
  for (int j = 0; j < 16; ++j){
    float wk[4], wa[4], wm[4], wq[4];
    ld4f(kw2  + (size_t)j*CC + c, wk);
    ld4f(aw2  + (size_t)j*CC + c, wa);
    ld4f(maw2 + (size_t)j*CC + c, wm);
    ld4f(mkw2 + (size_t)j*CC + c, wq);
    #pragma unroll
    for (int tt = 0; tt < 4; ++tt){
      float s1 = kt_l[tt][j], s2 = at_l[tt][j], s3 = mat_l[tt][j], s4 = mkt_l[tt][j];
      #pragma unroll
      for (int i = 0; i < 4; ++i){
        kkk[tt][i] += s1 * wk[i];
        aa[tt][i]  += s2 * wa[i];
        mam[tt][i] += s3 * wm[i];
        mkm[tt][i] += s4 * wq[i];
      }
    }
  }

  float td4[4], taa4[4], tma4[4], tmk4[4], fa4[4];
  ld4f(td + c, td4); ld4f(taa + c, taa4); ld4f(tma + c, tma4); ld4f(tmk + c, tmk4);
  ld4f(faaaa + c, fa4);

#define ELEM_TOKEN(TT_, E_, A_, B_, KF_, WD_) do{ \
    float k0a[4]; ld4bf(K0 + (E_), k0a); \
    float w2a[4]; ld4bf(W2A + (E_), w2a); \
    float ssq = 0.f; \
    _Pragma("unroll") \
    for (int i = 0; i < 4; ++i){ A_[i] = k0a[i] + kkk[TT_][i]; ssq += A_[i]*A_[i]; } \
    ssq = red16(ssq); \
    float rinv = 1.f / fmaxf(sqrtf(ssq), 1e-12f); \
    float outw_[4]; \
    _Pragma("unroll") \
    for (int i = 0; i < 4; ++i){ \
      float z  = td4[i] + w2a[i]; \
      float nz = -z; \
      float sp = (nz > 15.f) ? nz : log1pf(expf(nz)); \
      float w  = -sp - 0.5f; \
      float av  = sigm(taa4[i] + aa[TT_][i]); \
      float mav = sigm(tma4[i] + mam[TT_][i]); \
      float mkv = sigm(tmk4[i] + mkm[TT_][i]); \
      A_[i] *= rinv; \
      B_[i]  = -A_[i] * av; \
      KF_[i] = k0a[i] * (mav + av * (1.f - mav)) * expf(w * mkv); \
      float ou = -expf(w); \
      outw_[i] = ou; \
      if (WMODE == 1) WD_[i] = __expf(ou);              /* exact f32 w_t */ \
      else            WD_[i] = __expf(hval(f2h(ou)));   /* f16-consistent */ \
    } \
    st4bf(Bb + (E_), B_); \
    st4bf(K0 + (E_), KF_); \
    if (WMODE == 1) *(float4*)(WF + (E_)) = make_float4(WD_[0], WD_[1], WD_[2], WD_[3]); \
    else            st4h(UX + (E_), outw_); \
  }while(0)

  #pragma unroll
  for (int p = 0; p < 2; ++p){
    const int ttE = 2*p, ttO = ttE + 1;
    size_t eE = (size_t)(n0 + ttE) * CC + c;
    size_t eO = eE + CC;
    float aE[4], bE[4], kfE[4], wdE[4];
    float aO[4], bO[4], kfO[4], wdO[4];
    ELEM_TOKEN(ttE, eE, aE, bE, kfE, wdE);
    ELEM_TOKEN(ttO, eO, aO, bO, kfO, wdO);
    st4bf(KKN + eE, aE);

    float rE[4], rO[4];
    ld4bf(Rq + eE, rE); ld4bf(Rq + eO, rO);

    // rk for k_post (before R is overwritten)
    float rkE = red16(rE[0]*kfE[0]*fa4[0] + rE[1]*kfE[1]*fa4[1]
                    + rE[2]*kfE[2]*fa4[2] + rE[3]*kfE[3]*fa4[3]);
    float rkO = red16(rO[0]*kfO[0]*fa4[0] + rO[1]*kfO[1]*fa4[1]
                    + rO[2]*kfO[2]*fa4[2] + rO[3]*kfO[3]*fa4[3]);

    // u1 over KKN odd row
    float c1 = red16(dot4(bE, aO));
    float d  = red16(dot4(kfE, aO));
    float u1[4];
    #pragma unroll
    for (int i = 0; i < 4; ++i) u1[i] = wdE[i]*aO[i] + c1*aE[i];
    st4bf(KKN + eO, u1);

    // q' even
    float cq = red16(dot4(bE, rE));
    float e1 = red16(dot4(kfE, rE));
    float qe[4];
    #pragma unroll
    for (int i = 0; i < 4; ++i) qe[i] = wdE[i]*rE[i] + cq*aE[i];
    st4bf(Rq + eE, qe);

    // z = M_{t+1} q_{t+1}; q' odd = M_t z
    float cz  = red16(dot4(bO, rO));
    float e21 = red16(dot4(kfO, rO));
    float z[4];
    #pragma unroll
    for (int i = 0; i < 4; ++i) z[i] = wdO[i]*rO[i] + cz*aO[i];
    float cy  = red16(dot4(bE, z));
    float e20 = red16(dot4(kfE, z));
    float qo[4];
    #pragma unroll
    for (int i = 0; i < 4; ++i) qo[i] = wdE[i]*z[i] + cy*aE[i];
    st4bf(Rq + eO, qo);

    if (lg == 0){
      size_t pr = (size_t)((n0 + ttE) >> 1);
      float4 dv; dv.x = d; dv.y = e1; dv.z = e20; dv.w = e21;
      *(float4*)(Dsc + (pr * HH + h) * 4) = dv;
      RKsc[(size_t)(n0 + ttE) * HH + h] = rkE;
      RKsc[(size_t)(n0 + ttO) * HH + h] = rkO;
    }
  }
#undef ELEM_TOKEN
}

// ---------------------------------------------------------------------------
// Recurrence v13 (r8-validated): 32-lane rows, 2 waves/SIMD, pair-fused,
// all 4 reductions vs base S, f32 decay (WMODE=1).
// ---------------------------------------------------------------------------
template<int WMODE>
__global__ __launch_bounds__(256) void k_rec(const bf16u* __restrict__ Qp,
                                             const bf16u* __restrict__ WT,
                                             const float* __restrict__ WF,
                                             const bf16u* __restrict__ KFt,
                                             const bf16u* __restrict__ Vt,
                                             const bf16u* __restrict__ Aa,
                                             const bf16u* __restrict__ Bv,
                                             const float* __restrict__ Dsc,
                                             bf16u* __restrict__ Y){
  const int p   = blockIdx.x;                 // 0..511
  const int g   = (p & 7) | ((p >> 6) << 3);  // (b,h) group 0..63, XCD-clustered
  const int oct = (p >> 3) & 7;               // row octet within the head
  const int b   = g >> 4;
  const int h   = g & 15;
  const int tid = threadIdx.x;
  const int l31 = tid & 31;                   // 32 lanes per row
  const int i   = oct * 8 + (tid >> 5);       // state row 0..63
  const size_t base0 = (size_t)(b * TT) * CC + h * HSS;
  const size_t colb  = base0 + l31 * 2;       // 2 cols per lane
  const size_t rowb  = base0 + i;
  const size_t dscb  = ((size_t)(b * (TT/2)) * HH + h) * 4;

  float S0 = 0.f, S1 = 0.f;                   // state cols (2*l31, 2*l31+1)

  unsigned int qEA,qOA,aEA,uOA,kEA,kOA,bEA,bOA,wEA,wOA; float2 fEA,fOA; unsigned short vEA,vOA; float4 dA;
  unsigned int qEB,qOB,aEB,uOB,kEB,kOB,bEB,bOB,wEB,wOB; float2 fEB,fOB; unsigned short vEB,vOB; float4 dB;
  unsigned int qEC,qOC,aEC,uOC,kEC,kOC,bEC,bOC,wEC,wOC; float2 fEC,fOC; unsigned short vEC,vOC; float4 dC;
  unsigned int qED,qOD,aED,uOD,kED,kOD,bED,bOD,wED,wOD; float2 fED,fOD; unsigned short vED,vOD; float4 dD;

#define PL(S, T_) do{ \
    size_t cE_ = colb + (size_t)(T_) * CC, cO_ = cE_ + CC; \
    qE##S = *(const unsigned int*)(Qp  + cE_); qO##S = *(const unsigned int*)(Qp  + cO_); \
    aE##S = *(const unsigned int*)(Aa  + cE_); uO##S = *(const unsigned int*)(Aa  + cO_); \
    kE##S = *(const unsigned int*)(KFt + cE_); kO##S = *(const unsigned int*)(KFt + cO_); \
    bE##S = *(const unsigned int*)(Bv  + cE_); bO##S = *(const unsigned int*)(Bv  + cO_); \
    if (WMODE == 1){ \
      fE##S = *(const float2*)(WF + cE_); fO##S = *(const float2*)(WF + cO_); \
    } else { \
      wE##S = *(const unsigned int*)(WT + cE_); wO##S = *(const unsigned int*)(WT + cO_); \
    } \
    vE##S = Vt[rowb + (size_t)(T_) * CC]; \
    vO##S = Vt[rowb + (size_t)(T_ + 1) * CC]; \
    d##S  = *(const float4*)(Dsc + dscb + (size_t)((T_) >> 1) * (HH*4)); \
  }while(0)

#define PSTEP(S, T_) do{ \
    float a0=bflo(aE##S), a1=bfhi(aE##S); \
    float u0=bflo(uO##S), u1=bfhi(uO##S); \
    float g0=bflo(qE##S), g1=bfhi(qE##S); \
    float o0=bflo(qO##S), o1=bfhi(qO##S); \
    float pE_ = fmaf(S1, a1, S0 * a0); \
    float pO_ = fmaf(S1, u1, S0 * u0); \
    float yE_ = fmaf(S1, g1, S0 * g0); \
    float yO_ = fmaf(S1, o1, S0 * o0); \
    pE_ = red32(pE_); \
    pO_ = red32(pO_); \
    yE_ = red32(yE_); \
    yO_ = red32(yO_); \
    float vEf = bf2f(vE##S), vOf = bf2f(vO##S); \
    float saE = pE_; \
    float saO = fmaf(d##S.x, vEf, pO_); \
    float ypE = fmaf(d##S.y, vEf, yE_); \
    float ypO = fmaf(d##S.z, vEf, fmaf(d##S.w, vOf, yO_)); \
    float k0=bflo(kE##S), k1=bfhi(kE##S); \
    float b0=bflo(bE##S), b1=bfhi(bE##S); \
    float w0, w1; \
    if (WMODE == 1){ w0=fE##S.x; w1=fE##S.y; } \
    else { w0=__expf(hlo(wE##S)); w1=__expf(hhi(wE##S)); } \
    S0 = fmaf(S0, w0, fmaf(saE, b0, vEf * k0)); \
    S1 = fmaf(S1, w1, fmaf(saE, b1, vEf * k1)); \
    float ko0=bflo(kO##S), ko1=bfhi(kO##S); \
    float bo0=bflo(bO##S), bo1=bfhi(bO##S); \
    float wo0, wo1; \
    if (WMODE == 1){ wo0=fO##S.x; wo1=fO##S.y; } \
    else { wo0=__expf(hlo(wO##S)); wo1=__expf(hhi(wO##S)); } \
    S0 = fmaf(S0, wo0, fmaf(saO, bo0, vOf * ko0)); \
    S1 = fmaf(S1, wo1, fmaf(saO, bo1, vOf * ko1)); \
    if (l31 == 0){ \
      Y[rowb + (size_t)(T_) * CC]     = f2bf(ypE); \
      Y[rowb + (size_t)(T_ + 1) * CC] = f2bf(ypO); \
    } \
  }while(0)

  PL(A, 0); PL(B, 2); PL(C, 4); PL(D, 6);
  for (int t = 0; t < TT; t += 8){
    PSTEP(A, t);
    if (t + 8  < TT) PL(A, t + 8);
    PSTEP(B, t + 2);
    if (t + 10 < TT) PL(B, t + 10);
    PSTEP(C, t + 4);
    if (t + 12 < TT) PL(C, t + 12);
    PSTEP(D, t + 6);
    if (t + 14 < TT) PL(D, t + 14);
  }
#undef PL
#undef PSTEP
}

// ---------------------------------------------------------------------------
// Post: GroupNorm + precomputed bonus rk*v + precomputed gate GV -> YG (bf16)
// ---------------------------------------------------------------------------
__global__ __launch_bounds__(256) void k_post(const bf16u* __restrict__ Y,
                                              const bf16u* __restrict__ Vt,
                                              const bf16u* __restrict__ GV,
                                              const float* __restrict__ lnw,
                                              const float* __restrict__ lnb,
                                              const float* __restrict__ RKsc,
                                              bf16u* __restrict__ YG){
  int n = blockIdx.x, tid = threadIdx.x;
  int c = tid * 4;
  size_t e = (size_t)n * CC + c;

  float ya[4]; ld4bf(Y + e, ya);
  float s = ya[0] + ya[1] + ya[2] + ya[3];
  s = red16(s);
  float mu = s * (1.f / 64.f);
  float d[4], vs = 0.f;
  #pragma unroll
  for (int i = 0; i < 4; ++i){ d[i] = ya[i] - mu; vs += d[i] * d[i]; }
  vs = red16(vs);
  float rstd = rsqrtf(vs * (1.f / 64.f) + EPSGN);

  float rk = RKsc[(size_t)n * HH + (tid >> 4)];

  float va[4]; ld4bf(Vt + e, va);
  float lw4[4], lb4[4];
  ld4f(lnw + c, lw4); ld4f(lnb + c, lb4);
  float g[4]; ld4bf(GV + e, g);
  float o[4];
  #pragma unroll
  for (int i = 0; i < 4; ++i){
    float yn = d[i] * rstd * lw4[i] + lb4[i] + rk * va[i];
    o[i] = yn * g[i];
  }
  st4bf(YG + e, o);
}

// ---------------------------------------------------------------------------
extern "C" void kernel_launch(void* const* d_in, const int* in_sizes, int n_in,
                              void* d_out, int out_size, void* d_ws, size_t ws_size,
                              hipStream_t stream){
  (void)in_sizes; (void)n_in; (void)out_size;
  const float* x        = (const float*)d_in[0];
  const float* tmx      = (const float*)d_in[1];
  const float* tmaa     = (const float*)d_in[2];
  const float* maa_w1   = (const float*)d_in[3];
  const float* maa_w2   = (const float*)d_in[4];
  const float* decay_w1 = (const float*)d_in[5];
  const float* decay_w2 = (const float*)d_in[6];
  const float* aaa_w1   = (const float*)d_in[7];
  const float* aaa_w2   = (const float*)d_in[8];
  const float* kkk_w1   = (const float*)d_in[9];
  const float* kkk_w2   = (const float*)d_in[10];
  const float* gate_w1  = (const float*)d_in[11];
  const float* gate_w2  = (const float*)d_in[12];
  const float* ma_w1    = (const float*)d_in[13];
  const float* ma_w2    = (const float*)d_in[14];
  const float* mk_w1    = (const float*)d_in[15];
  const float* mk_w2    = (const float*)d_in[16];
  const float* t_decay  = (const float*)d_in[17];
  const float* t_faaaa  = (const float*)d_in[18];
  const float* t_aaaaa  = (const float*)d_in[19];
  const float* t_misc_a = (const float*)d_in[20];
  const float* t_misc_k = (const float*)d_in[21];
  const float* Wr       = (const float*)d_in[22];
  const float* Wk       = (const float*)d_in[23];
  const float* Wv       = (const float*)d_in[24];
  const float* Wo       = (const float*)d_in[25];
  const float* ln_w     = (const float*)d_in[26];
  const float* ln_b     = (const float*)d_in[27];

  // Slot map (8MiB bf16 each), 56 MiB slots + smalls at 56..60 MiB.
  // 60..76 MiB region time-shared: phase A (weights) -> phase B (WF).
  // WoB/GW2T live in S2 (UX slot, dead in fast path), written by k_elem.
  bf16u* bw  = (bf16u*)d_ws;
  bf16u* MIX = bw + 0*SLOT;
  bf16u* X0  = bw + 0*SLOT;
  bf16u* KKN = bw + 0*SLOT;
  bf16u* YG  = bw + 0*SLOT;
  bf16u* X1  = bw + 1*SLOT;
  bf16u* Bb  = bw + 1*SLOT;
  bf16u* GV  = bw + 1*SLOT;
  bf16u* X2  = bw + 2*SLOT;
  bf16u* UX  = bw + 2*SLOT;
  bf16u* X3  = bw + 3*SLOT;
  bf16u* W2A = bw + 3*SLOT;
  bf16u* Yb  = bw + 3*SLOT;
  bf16u* R   = bw + 4*SLOT;   // becomes q'
  bf16u* K0  = bw + 5*SLOT;   // becomes KF
  bf16u* V   = bw + 6*SLOT;
  char*  wsb = (char*)d_ws;
  bf16u* LO  = (bf16u*)(wsb + (56ull<<20));   // [N,128] bf16, 1 MiB
  bf16u* GT  = (bf16u*)(wsb + (57ull<<20));   // [N,128] bf16, 1 MiB
  bf16u* P1  = (bf16u*)(wsb + (58ull<<20));   // [N,96]  bf16 (dt|at|ma)
  bf16u* P2  = (bf16u*)(wsb + (58ull<<20) + (768ull<<10)); // [N,32] bf16
  float* Dsc = (float*)(wsb + (59ull<<20));   // [N/2,16] float4, 512 KiB
  float* RKsc= (float*)(wsb + (59ull<<20) + (512ull<<10)); // [N,16] f32, 256 KiB
  float* WF  = (float*)(wsb + (60ull<<20));   // [N,CC] f32 w_t, 16 MiB
  bf16u* WrB = (bf16u*)(wsb + (60ull<<20));
  bf16u* WkB = (bf16u*)(wsb + (62ull<<20));
  bf16u* WvB = (bf16u*)(wsb + (64ull<<20));
  bf16u* W1B = (bf16u*)(wsb + (66ull<<20));   // 384 rows x 1024, 0.75 MiB
  bf16u* W2TB= (bf16u*)(wsb + (67ull<<20));   // [1024][192], 0.375 MiB
  bf16u* WoB = UX;                            // S2 (dead in fast path), 2 MiB
  bf16u* GW2T= UX + 1048576;                  // S2 + 2 MiB: [1024][128] bf16
  const bool fast = ws_size >= (77ull<<20);

  if (fast){
    // 0+1. merged mix + weight pre-conversion (bf16; identical RNE rounding)
    k_prep_wconv<<<7744, 256, 0, stream>>>(x, tmx, MIX,
                                           Wr, Wk, Wv, maa_w1, gate_w1, decay_w1,
                                           aaa_w1, ma_w1, kkk_w1, mk_w1,
                                           maa_w2, decay_w2,
                                           WrB, WkB, WvB, W1B, W2TB);
    // 2. lo = tanh(mix @ maa_w1^T)  (reads MIX — r12 structure restored)
    k_gemm_b64<true><<<dim3(1,64),256,0,stream>>>(MIX, W1B, LO, 128, CC, 128);
    // 3. xm[g]: 4 NN-GEMMs merged into one launch (grid.z = group)
    k_gemm_nn_b4<<<dim3(8,32,4),256,0,stream>>>(LO, W2TB, X0, x, tmaa);
    // 4. big projections merged (z=3, 1536 blocks, BK=64 pipelined)
    k_gemm_b64_rkv<<<dim3(8,64,3),256,0,stream>>>(X0, X2, X3, WrB, WkB, WvB,
                                                  R, K0, V);
    // 5. LoRA projections merged into one launch (grid.z = which)
    k_gemm_b64_lora<<<dim3(1,64,3),256,0,stream>>>(X0, X1, X2, W1B, GT, P1, P2);
    // 6. W2A = P1[:, :64] @ decay_w2 (last read of W2TB before WF overwrites)
    k_gemm_nn_b<64,0><<<dim3(8,32),256,0,stream>>>(P1, 96, W2TB, 128, W2A, nullptr, nullptr);
    // 7. fused elementwise + pair precompute + Wo/gate_w2 conversion
    k_elem<1><<<2560, 256, 0, stream>>>(K0, P1, P2, W2A,
                                        kkk_w2, aaa_w2, ma_w2, mk_w2,
                                        t_decay, t_aaaaa, t_misc_a, t_misc_k, t_faaaa,
                                        KKN, Bb, UX, WF, R, Dsc, RKsc,
                                        Wo, gate_w2, WoB, GW2T);
    // 8. delta-rule recurrence (r8-validated v13)
    k_rec<1><<<512, 256, 0, stream>>>(R, UX, WF, K0, V, KKN, Bb, Dsc, Yb);
    // 9. GV = GT @ gate_w2 (BK=64 fast NT path; GW2T from step 7)
    k_gemm_b64<true><<<dim3(8,64),256,0,stream>>>(GT, GW2T, GV, CC, 128, 0);
    // 10. groupnorm + bonus + gate
    k_post<<<4096, 256, 0, stream>>>(Yb, V, GV, ln_w, ln_b, RKsc, YG);
    // 11. out = yg @ Wo^T -> f32 (WoB from step 7, lives in S2)
    k_gemm_b64<false><<<dim3(8,64),256,0,stream>>>(YG, WoB, d_out, CC, CC, 0);
  } else {
    // Fallback: exact r8 sequence (f32 weights in-GEMM, f16 -u decay).
    k_prep<<<4096, 256, 0, stream>>>(x, tmx, MIX);
    k_gemm_mfma<true><<<dim3(1,32),256,0,stream>>>(MIX, maa_w1, maa_w1, maa_w1,
                                                   128, 128, LO, 128, CC, 128);
    bf16u* XMs[4] = {X0, X1, X2, X3};
    for (int g = 0; g < 4; ++g)
      k_gemm_nn<32,1><<<dim3(8,32),256,0,stream>>>(LO + g*32, 128,
                                                   maa_w2 + (size_t)g*32*CC,
                                                   XMs[g], x, tmaa + (size_t)g*CC);
    k_gemm_mfma<true><<<dim3(8,32),256,0,stream>>>(X0, Wr, Wr, Wr, CC, CC, R,  CC, CC, 0);
    k_gemm_mfma<true><<<dim3(8,32),256,0,stream>>>(X2, Wk, Wk, Wk, CC, CC, K0, CC, CC, 0);
    k_gemm_mfma<true><<<dim3(8,32),256,0,stream>>>(X3, Wv, Wv, Wv, CC, CC, V,  CC, CC, 0);
    k_gemm_mfma<true><<<dim3(1,32),256,0,stream>>>(X0, gate_w1, gate_w1, gate_w1,
                                                   128, 128, GT, 128, CC, 128);
    k_gemm_mfma<true><<<dim3(1,32),256,0,stream>>>(X1, decay_w1, aaa_w1, ma_w1,
                                                   64, 80, P1, 96, CC, 64);
    k_gemm_mfma<true><<<dim3(1,32),256,0,stream>>>(X2, kkk_w1, mk_w1, mk_w1,
                                                   16, 32, P2, 32, CC, 16);
    k_gemm_nn<64,0><<<dim3(8,32),256,0,stream>>>(P1, 96, decay_w2, W2A, nullptr, nullptr);
    k_elem<0><<<1024, 256, 0, stream>>>(K0, P1, P2, W2A,
                                        kkk_w2, aaa_w2, ma_w2, mk_w2,
                                        t_decay, t_aaaaa, t_misc_a, t_misc_k, t_faaaa,
                                        KKN, Bb, UX, WF, R, Dsc, RKsc,
                                        Wo, gate_w2, WoB, GW2T);
    k_rec<0><<<512, 256, 0, stream>>>(R, UX, WF, K0, V, KKN, Bb, Dsc, Yb);
    k_gemm_nn<128,0><<<dim3(8,32),256,0,stream>>>(GT, 128, gate_w2, GV, nullptr, nullptr);
    k_post<<<4096, 256, 0, stream>>>(Yb, V, GV, ln_w, ln_b, RKsc, YG);
    k_gemm_mfma<false><<<dim3(8,32),256,0,stream>>>(YG, Wo, Wo, Wo, CC, CC, d_out, CC, CC, 0);
  }
}

// Round 15
// 566.527 us; speedup vs baseline: 1.3477x; 1.0012x over previous
//
#include <hip/hip_runtime.h>
#include <cstdint>
#include <cstddef>

// Problem constants
#define BB   4
#define TT   1024
#define CC   1024
#define HH   16
#define HSS  64
#define NNtok 4096            // B*T
#define EPSGN 0.00064f
#define W2TS 192              // W2TB col count (maa_w2 128 | decay_w2 64)

typedef unsigned short bf16u;
typedef __attribute__((ext_vector_type(8))) short short8;
typedef __attribute__((ext_vector_type(4))) float f32x4;
#define SLOT 4194304ull       // elements per 8MiB bf16 slot (= NNtok*CC)

__device__ __forceinline__ float bf2f(bf16u u){
  union { unsigned int i; float f; } cv; cv.i = ((unsigned int)u) << 16; return cv.f;
}
__device__ __forceinline__ unsigned short f2bfbits(unsigned int x){
  return (unsigned short)((x + 0x7fffu + ((x >> 16) & 1u)) >> 16);   // RNE
}
__device__ __forceinline__ bf16u f2bf(float f){
  union { float f; unsigned int i; } cv; cv.f = f;
  return f2bfbits(cv.i);
}
__device__ __forceinline__ void ld4bf(const bf16u* p, float* o){
  ushort4 u = *reinterpret_cast<const ushort4*>(p);
  o[0]=bf2f(u.x); o[1]=bf2f(u.y); o[2]=bf2f(u.z); o[3]=bf2f(u.w);
}
__device__ __forceinline__ void st4bf(bf16u* p, const float* v){
  ushort4 u; u.x=f2bf(v[0]); u.y=f2bf(v[1]); u.z=f2bf(v[2]); u.w=f2bf(v[3]);
  *reinterpret_cast<ushort4*>(p) = u;
}
__device__ __forceinline__ unsigned short f2h(float f){
  union { _Float16 h; unsigned short s; } c; c.h = (_Float16)f; return c.s;
}
__device__ __forceinline__ void st4h(bf16u* p, const float* v){
  ushort4 u; u.x=f2h(v[0]); u.y=f2h(v[1]); u.z=f2h(v[2]); u.w=f2h(v[3]);
  *reinterpret_cast<ushort4*>(p) = u;
}
__device__ __forceinline__ void ld4f(const float* p, float* o){
  float4 v = *reinterpret_cast<const float4*>(p);
  o[0]=v.x; o[1]=v.y; o[2]=v.z; o[3]=v.w;
}
__device__ __forceinline__ float sigm(float x){ return 1.f / (1.f + expf(-x)); }

// unpack helpers
__device__ __forceinline__ float bflo(unsigned int u){
  union { unsigned int i; float f; } c; c.i = u << 16; return c.f;
}
__device__ __forceinline__ float bfhi(unsigned int u){
  union { unsigned int i; float f; } c; c.i = u & 0xffff0000u; return c.f;
}
__device__ __forceinline__ float hlo(unsigned int u){
  union { unsigned short s; _Float16 h; } c; c.s = (unsigned short)(u & 0xffffu); return (float)c.h;
}
__device__ __forceinline__ float hhi(unsigned int u){
  union { unsigned short s; _Float16 h; } c; c.s = (unsigned short)(u >> 16); return (float)c.h;
}
__device__ __forceinline__ float hval(unsigned short s){
  union { unsigned short s; _Float16 h; } c; c.s = s; return (float)c.h;
}
__device__ __forceinline__ float dot4(const float* x, const float* y){
  return (x[0]*y[0] + x[1]*y[1]) + (x[2]*y[2] + x[3]*y[3]);
}

// 16-lane sum via DPP. old=0 + bound_ctrl=1 folds to single v_add_f32_dpp.
template<int CTRL>
__device__ __forceinline__ float dpp_add(float v){
  union { float f; int i; } a, b;
  a.f = v;
  b.i = __builtin_amdgcn_update_dpp(0, a.i, CTRL, 0xF, 0xF, true);
  return v + b.f;
}
__device__ __forceinline__ float red16(float v){
  v = dpp_add<0xB1>(v);    // quad_perm [1,0,3,2]  (xor 1)
  v = dpp_add<0x4E>(v);    // quad_perm [2,3,0,1]  (xor 2)
  v = dpp_add<0x124>(v);   // row_ror:4
  v = dpp_add<0x128>(v);   // row_ror:8
  return v;
}
// 32-lane sum in all lanes: red16 then exchange complementary 16-rows
// between two DISTINCT-register copies (laundered; rounds 1/3 failed when
// regalloc coalesced both operands into one phys reg -> self-swap).
__device__ __forceinline__ float red32(float v){
  v = red16(v);
  union { float f; int i; } x, y;
  x.f = v; y.f = v;
  asm volatile("" : "+v"(y.i));   // distinct-vreg launder
  asm volatile("v_permlane16_swap_b32 %0, %1" : "+v"(x.i), "+v"(y.i));
  return x.f + y.f;
}

// ---------------------------------------------------------------------------
// mix = x + (x[t-1]-x[t])*time_maa_x  (x[-1]=0), stored bf16 (fallback path)
// ---------------------------------------------------------------------------
__global__ __launch_bounds__(256) void k_prep(const float* __restrict__ x,
                                              const float* __restrict__ tmx,
                                              bf16u* __restrict__ MIX){
  int e = (blockIdx.x * 256 + threadIdx.x) * 4;
  int n = e >> 10;
  int c = e & (CC - 1);
  int t = n & (TT - 1);
  float xf[4]; ld4f(x + e, xf);
  float pf[4] = {0.f, 0.f, 0.f, 0.f};
  if (t > 0) ld4f(x + e - CC, pf);
  float tm[4]; ld4f(tmx + c, tm);
  float mv[4];
  #pragma unroll
  for (int i = 0; i < 4; ++i) mv[i] = xf[i] + (pf[i] - xf[i]) * tm[i];
  st4bf(MIX + e, mv);
}

// ---------------------------------------------------------------------------
// MERGED prep + weight pre-conversion. blk<4096: mix; else: weight convert.
// ---------------------------------------------------------------------------
__global__ __launch_bounds__(256) void k_prep_wconv(
    const float* __restrict__ x, const float* __restrict__ tmx,
    bf16u* __restrict__ MIX,
    const float* __restrict__ Wr, const float* __restrict__ Wk,
    const float* __restrict__ Wv,
    const float* __restrict__ maa_w1, const float* __restrict__ gate_w1,
    const float* __restrict__ decay_w1, const float* __restrict__ aaa_w1,
    const float* __restrict__ ma_w1, const float* __restrict__ kkk_w1,
    const float* __restrict__ mk_w1,
    const float* __restrict__ maa_w2, const float* __restrict__ decay_w2,
    bf16u* __restrict__ WrB, bf16u* __restrict__ WkB, bf16u* __restrict__ WvB,
    bf16u* __restrict__ W1B, bf16u* __restrict__ W2TB){
  int tid = threadIdx.x;
  if (blockIdx.x < 4096){
    int e = (blockIdx.x * 256 + tid) * 4;
    int n = e >> 10;
    int c = e & (CC - 1);
    int t = n & (TT - 1);
    float xf[4]; ld4f(x + e, xf);
    float pf[4] = {0.f, 0.f, 0.f, 0.f};
    if (t > 0) ld4f(x + e - CC, pf);
    float tm[4]; ld4f(tmx + c, tm);
    float mv[4];
    #pragma unroll
    for (int i = 0; i < 4; ++i) mv[i] = xf[i] + (pf[i] - xf[i]) * tm[i];
    st4bf(MIX + e, mv);
    return;
  }
  int blk = blockIdx.x - 4096;
  if (blk < 3072){
    const float* src = (blk < 1024) ? Wr : (blk < 2048) ? Wk : Wv;
    bf16u* dst = (blk < 1024) ? WrB : (blk < 2048) ? WkB : WvB;
    size_t e = (size_t)(blk & 1023) * 1024 + (size_t)tid * 4;
    float v[4]; ld4f(src + e, v);
    st4bf(dst + e, v);
  } else if (blk < 3456){
    int row = blk - 3072;
    const float* src;
    if      (row < 128) src = maa_w1   + (size_t)row * 1024;
    else if (row < 256) src = gate_w1  + (size_t)(row - 128) * 1024;
    else if (row < 320) src = decay_w1 + (size_t)(row - 256) * 1024;
    else if (row < 336) src = aaa_w1   + (size_t)(row - 320) * 1024;
    else if (row < 352) src = ma_w1    + (size_t)(row - 336) * 1024;
    else if (row < 368) src = kkk_w1   + (size_t)(row - 352) * 1024;
    else                src = mk_w1    + (size_t)(row - 368) * 1024;
    float v[4]; ld4f(src + tid * 4, v);
    st4bf(W1B + (size_t)row * 1024 + tid * 4, v);
  } else {
    int j = blk - 3456;   // 0..191
    const float* src = (j < 128) ? (maa_w2 + (size_t)j * 1024)
                                 : (decay_w2 + (size_t)(j - 128) * 1024);
    for (int c = tid; c < 1024; c += 256)
      W2TB[(size_t)c * W2TS + j] = f2bf(src[c]);
  }
}

// ---------------------------------------------------------------------------
// MFMA NT GEMM body, bf16-W, M64xN128, BK=64 double-K staging (general use).
// ---------------------------------------------------------------------------
#define B64_AROW 72
#define B64_ASZ (64*72)
#define B64_BSZ (128*72)
template<bool OB>
__device__ __forceinline__ void gemm_b64_body(const bf16u* __restrict__ X,
                                              const bf16u* __restrict__ WB,
                                              void* __restrict__ OUTv,
                                              int Nd, int Kd, int act_n,
                                              short* __restrict__ As,
                                              short* __restrict__ Bs,
                                              int bn0, int bm0){
  const int tid  = threadIdx.x;
  const int lane = tid & 63;
  const int wv   = tid >> 6;
  const int wm   = wv >> 1, wn = wv & 1;   // wave -> 32-row x 64-col subtile
  const int l15  = lane & 15;
  const int quad = lane >> 4;

  f32x4 acc[2][4];
  #pragma unroll
  for (int mi = 0; mi < 2; ++mi)
    #pragma unroll
    for (int ni = 0; ni < 4; ++ni)
      #pragma unroll
      for (int rg = 0; rg < 4; ++rg) acc[mi][ni][rg] = 0.f;

  const int ra = tid >> 2, k0a = (tid & 3) * 16;   // A: 64 rows x 64k, 2 uint4/thr
  const int rb = tid >> 1, k0b = (tid & 1) * 32;   // B: 128 rows x 64k, 4 uint4/thr
  const bf16u* xsrc = X + (size_t)(bm0 + ra) * Kd;
  const bf16u* wsrc = (bn0 + rb < Nd) ? WB + (size_t)(bn0 + rb) * Kd : nullptr;

  uint4 xa0 = *(const uint4*)(xsrc + k0a);
  uint4 xa1 = *(const uint4*)(xsrc + k0a + 8);
  uint4 wa0 = make_uint4(0,0,0,0), wa1 = wa0, wa2 = wa0, wa3 = wa0;
  if (wsrc){
    wa0 = *(const uint4*)(wsrc + k0b);
    wa1 = *(const uint4*)(wsrc + k0b + 8);
    wa2 = *(const uint4*)(wsrc + k0b + 16);
    wa3 = *(const uint4*)(wsrc + k0b + 24);
  }
  *(uint4*)&As[ra * B64_AROW + k0a]      = xa0;
  *(uint4*)&As[ra * B64_AROW + k0a + 8]  = xa1;
  *(uint4*)&Bs[rb * B64_AROW + k0b]      = wa0;
  *(uint4*)&Bs[rb * B64_AROW + k0b + 8]  = wa1;
  *(uint4*)&Bs[rb * B64_AROW + k0b + 16] = wa2;
  *(uint4*)&Bs[rb * B64_AROW + k0b + 24] = wa3;
  __syncthreads();

  const int NS = Kd >> 6;
  for (int s = 0; s < NS; ++s){
    const int cur = s & 1;
    if (s + 1 < NS){                    // issue next-stage loads BEFORE compute
      int kb = (s + 1) << 6;
      xa0 = *(const uint4*)(xsrc + kb + k0a);
      xa1 = *(const uint4*)(xsrc + kb + k0a + 8);
      if (wsrc){
        wa0 = *(const uint4*)(wsrc + kb + k0b);
        wa1 = *(const uint4*)(wsrc + kb + k0b + 8);
        wa2 = *(const uint4*)(wsrc + kb + k0b + 16);
        wa3 = *(const uint4*)(wsrc + kb + k0b + 24);
      }
    }
    #pragma unroll
    for (int kk = 0; kk < 64; kk += 32){
      short8 af[2], bfg[4];
      #pragma unroll
      for (int mi = 0; mi < 2; ++mi)
        af[mi] = *(const short8*)&As[cur*B64_ASZ + (wm*32 + mi*16 + l15) * B64_AROW + kk + quad*8];
      #pragma unroll
      for (int ni = 0; ni < 4; ++ni)
        bfg[ni] = *(const short8*)&Bs[cur*B64_BSZ + (wn*64 + ni*16 + l15) * B64_AROW + kk + quad*8];
      #pragma unroll
      for (int mi = 0; mi < 2; ++mi)
        #pragma unroll
        for (int ni = 0; ni < 4; ++ni)
          acc[mi][ni] = __builtin_amdgcn_mfma_f32_16x16x32_bf16(af[mi], bfg[ni], acc[mi][ni], 0, 0, 0);
    }
    if (s + 1 < NS){
      const int nxt = cur ^ 1;
      *(uint4*)&As[nxt*B64_ASZ + ra * B64_AROW + k0a]      = xa0;
      *(uint4*)&As[nxt*B64_ASZ + ra * B64_AROW + k0a + 8]  = xa1;
      *(uint4*)&Bs[nxt*B64_BSZ + rb * B64_AROW + k0b]      = wa0;
      *(uint4*)&Bs[nxt*B64_BSZ + rb * B64_AROW + k0b + 8]  = wa1;
      *(uint4*)&Bs[nxt*B64_BSZ + rb * B64_AROW + k0b + 16] = wa2;
      *(uint4*)&Bs[nxt*B64_BSZ + rb * B64_AROW + k0b + 24] = wa3;
      __syncthreads();
    }
  }

  #pragma unroll
  for (int mi = 0; mi < 2; ++mi){
    #pragma unroll
    for (int ni = 0; ni < 4; ++ni){
      int col = bn0 + wn*64 + ni*16 + l15;
      if (col >= Nd) continue;
      #pragma unroll
      for (int rg = 0; rg < 4; ++rg){
        int row = bm0 + wm*32 + mi*16 + quad*4 + rg;
        float v = acc[mi][ni][rg];
        if (col < act_n) v = tanhf(v);
        if (OB) ((bf16u*)OUTv)[(size_t)row * Nd + col] = f2bf(v);
        else    ((float*)OUTv)[(size_t)row * Nd + col] = v;
      }
    }
  }
}

template<bool OB>
__global__ __launch_bounds__(256) void k_gemm_b64(const bf16u* __restrict__ X,
                                                  const bf16u* __restrict__ WB,
                                                  void* __restrict__ OUTv,
                                                  int Nd, int Kd, int act_n){
  __shared__ short As[2*B64_ASZ];
  __shared__ short Bs[2*B64_BSZ];
  gemm_b64_body<OB>(X, WB, OUTv, Nd, Kd, act_n, As, Bs,
                    blockIdx.x * 128, blockIdx.y * 64);
}

// ---------------------------------------------------------------------------
// MFMA NT GEMM body, bf16-W, M128xN128, BK=32 ping-pong (r10-verified body,
// r15): square 64x64 wave-tile -> 16 MFMA per 8 ds_read_b128 (ratio 2.0 vs
// M64's 1.33 — the M64 tile is LDS-pipe-bound: 144 LDS-cyc vs 78 MFMA-cyc
// per 32-K step). Only used in the merged z=3 rkv launch, where 768 blocks
// = exactly 3 co-resident blocks/CU (LDS 40KB, 3x40=120<=160KB) -> 3
// waves/SIMD, beating M64's 2. Same BK32 k-order -> bitwise identical.
// ---------------------------------------------------------------------------
#define B128_SZ (128*40)
template<bool OB>
__device__ __forceinline__ void gemm_b128_body(const bf16u* __restrict__ X,
                                               const bf16u* __restrict__ WB,
                                               void* __restrict__ OUTv,
                                               int Nd, int Kd, int act_n,
                                               short* __restrict__ As,
                                               short* __restrict__ Bs,
                                               int bn0, int bm0){
  const int tid  = threadIdx.x;
  const int lane = tid & 63;
  const int wv   = tid >> 6;
  const int wm   = wv >> 1, wn = wv & 1;   // wave -> 64x64 subtile
  const int l15  = lane & 15;
  const int quad = lane >> 4;

  f32x4 acc[4][4];
  #pragma unroll
  for (int mi = 0; mi < 4; ++mi)
    #pragma unroll
    for (int ni = 0; ni < 4; ++ni)
      #pragma unroll
      for (int rg = 0; rg < 4; ++rg) acc[mi][ni][rg] = 0.f;

  const int r    = tid >> 1;
  const int half = (tid & 1) * 16;
  const bf16u* wsrc = (bn0 + r < Nd) ? WB + (size_t)(bn0 + r) * Kd : nullptr;
  const bf16u* xsrc = X + (size_t)(bm0 + r) * Kd;

  uint4 xa = *(const uint4*)(xsrc + half);
  uint4 xb = *(const uint4*)(xsrc + half + 8);
  uint4 wa = make_uint4(0,0,0,0), wb = wa;
  if (wsrc){
    wa = *(const uint4*)(wsrc + half);
    wb = *(const uint4*)(wsrc + half + 8);
  }
  *(uint4*)&As[r * 40 + half]     = xa;
  *(uint4*)&As[r * 40 + half + 8] = xb;
  *(uint4*)&Bs[r * 40 + half]     = wa;
  *(uint4*)&Bs[r * 40 + half + 8] = wb;
  __syncthreads();

  const int NK = Kd >> 5;
  for (int k = 0; k < NK; ++k){
    const int cur = k & 1;
    if (k + 1 < NK){                    // issue next-tile loads BEFORE compute
      int k0 = (k + 1) << 5;
      xa = *(const uint4*)(xsrc + k0 + half);
      xb = *(const uint4*)(xsrc + k0 + half + 8);
      if (wsrc){
        wa = *(const uint4*)(wsrc + k0 + half);
        wb = *(const uint4*)(wsrc + k0 + half + 8);
      }
    }
    short8 af[4], bfg[4];
    #pragma unroll
    for (int mi = 0; mi < 4; ++mi)
      af[mi] = *(const short8*)&As[cur*B128_SZ + (wm*64 + mi*16 + l15) * 40 + quad*8];
    #pragma unroll
    for (int ni = 0; ni < 4; ++ni)
      bfg[ni] = *(const short8*)&Bs[cur*B128_SZ + (wn*64 + ni*16 + l15) * 40 + quad*8];
    #pragma unroll
    for (int mi = 0; mi < 4; ++mi)
      #pragma unroll
      for (int ni = 0; ni < 4; ++ni)
        acc[mi][ni] = __builtin_amdgcn_mfma_f32_16x16x32_bf16(af[mi], bfg[ni], acc[mi][ni], 0, 0, 0);
    if (k + 1 < NK){
      const int nxt = cur ^ 1;
      *(uint4*)&As[nxt*B128_SZ + r * 40 + half]     = xa;
      *(uint4*)&As[nxt*B128_SZ + r * 40 + half + 8] = xb;
      *(uint4*)&Bs[nxt*B128_SZ + r * 40 + half]     = wa;
      *(uint4*)&Bs[nxt*B128_SZ + r * 40 + half + 8] = wb;
      __syncthreads();
    }
  }

  #pragma unroll
  for (int mi = 0; mi < 4; ++mi){
    #pragma unroll
    for (int ni = 0; ni < 4; ++ni){
      int col = bn0 + wn*64 + ni*16 + l15;
      if (col >= Nd) continue;
      #pragma unroll
      for (int rg = 0; rg < 4; ++rg){
        int row = bm0 + wm*64 + mi*16 + quad*4 + rg;
        float v = acc[mi][ni][rg];
        if (col < act_n) v = tanhf(v);
        if (OB) ((bf16u*)OUTv)[(size_t)row * Nd + col] = f2bf(v);
        else    ((float*)OUTv)[(size_t)row * Nd + col] = v;
      }
    }
  }
}

// R/K/V big projections merged into one z=3 launch using the M128 body:
// grid (8,32,3) = 768 blocks = 3 co-resident blocks/CU (LDS 40KB).
__global__ __launch_bounds__(256) void k_gemm_b128_rkv(const bf16u* __restrict__ X0,
                                                       const bf16u* __restrict__ X2,
                                                       const bf16u* __restrict__ X3,
                                                       const bf16u* __restrict__ WrB,
                                                       const bf16u* __restrict__ WkB,
                                                       const bf16u* __restrict__ WvB,
                                                       bf16u* __restrict__ R,
                                                       bf16u* __restrict__ K0,
                                                       bf16u* __restrict__ V){
  __shared__ short As[2*B128_SZ];
  __shared__ short Bs[2*B128_SZ];
  const int z = blockIdx.z;
  const int bn0 = blockIdx.x * 128, bm0 = blockIdx.y * 128;
  if (z == 0)      gemm_b128_body<true>(X0, WrB, R,  CC, CC, 0, As, Bs, bn0, bm0);
  else if (z == 1) gemm_b128_body<true>(X2, WkB, K0, CC, CC, 0, As, Bs, bn0, bm0);
  else             gemm_b128_body<true>(X3, WvB, V,  CC, CC, 0, As, Bs, bn0, bm0);
}

// 3 LoRA projections merged into one launch (z decodes).
__global__ __launch_bounds__(256) void k_gemm_b64_lora(const bf16u* __restrict__ X0,
                                                       const bf16u* __restrict__ X1,
                                                       const bf16u* __restrict__ X2,
                                                       const bf16u* __restrict__ W1B,
                                                       bf16u* __restrict__ GT,
                                                       bf16u* __restrict__ P1,
                                                       bf16u* __restrict__ P2){
  __shared__ short As[2*B64_ASZ];
  __shared__ short Bs[2*B64_BSZ];
  const int z = blockIdx.z;
  const int bm0 = blockIdx.y * 64;
  if (z == 0)
    gemm_b64_body<true>(X0, W1B + 128*1024, GT, 128, CC, 128, As, Bs, 0, bm0);
  else if (z == 1)
    gemm_b64_body<true>(X1, W1B + 256*1024, P1, 96, CC, 64, As, Bs, 0, bm0);
  else
    gemm_b64_body<true>(X2, W1B + 352*1024, P2, 32, CC, 16, As, Bs, 0, bm0);
}

// ---------------------------------------------------------------------------
// MFMA NN GEMM body, pre-transposed bf16 B (single-staging; K fits in LDS).
// ---------------------------------------------------------------------------
template<int KD, int EP>
__device__ __forceinline__ void gemm_nn_body(const bf16u* __restrict__ A, int lda,
                                             const bf16u* __restrict__ BT, int koff,
                                             bf16u* __restrict__ OUT,
                                             const float* __restrict__ x,
                                             const float* __restrict__ tma_g,
                                             short* __restrict__ As,
                                             short* __restrict__ Bs,
                                             int bn0, int bm0){
  const int tid  = threadIdx.x;
  const int lane = tid & 63;
  const int wv   = tid >> 6;
  const int wm   = wv >> 1, wn = wv & 1;
  const int l15  = lane & 15;
  const int quad = lane >> 4;

  for (int idx = tid; idx < 128 * (KD / 8); idx += 256){
    int r  = idx / (KD / 8);
    int kc = (idx % (KD / 8)) * 8;
    *(uint4*)&As[r * (KD + 8) + kc] =
        *(const uint4*)(A + (size_t)(bm0 + r) * lda + kc);
  }
  for (int idx = tid; idx < 128 * (KD / 8); idx += 256){
    int cc_ = idx / (KD / 8);
    int kc  = (idx % (KD / 8)) * 8;
    *(uint4*)&Bs[cc_ * (KD + 8) + kc] =
        *(const uint4*)(BT + (size_t)(bn0 + cc_) * W2TS + koff + kc);
  }
  __syncthreads();

  f32x4 acc[4][4];
  #pragma unroll
  for (int mi = 0; mi < 4; ++mi)
    #pragma unroll
    for (int ni = 0; ni < 4; ++ni)
      #pragma unroll
      for (int rg = 0; rg < 4; ++rg) acc[mi][ni][rg] = 0.f;

  #pragma unroll
  for (int kk = 0; kk < KD; kk += 32){
    short8 af[4], bfg[4];
    #pragma unroll
    for (int mi = 0; mi < 4; ++mi)
      af[mi] = *(const short8*)&As[(wm*64 + mi*16 + l15) * (KD + 8) + kk + quad*8];
    #pragma unroll
    for (int ni = 0; ni < 4; ++ni)
      bfg[ni] = *(const short8*)&Bs[(wn*64 + ni*16 + l15) * (KD + 8) + kk + quad*8];
    #pragma unroll
    for (int mi = 0; mi < 4; ++mi)
      #pragma unroll
      for (int ni = 0; ni < 4; ++ni)
        acc[mi][ni] = __builtin_amdgcn_mfma_f32_16x16x32_bf16(af[mi], bfg[ni], acc[mi][ni], 0, 0, 0);
  }

  #pragma unroll
  for (int mi = 0; mi < 4; ++mi){
    #pragma unroll
    for (int ni = 0; ni < 4; ++ni){
      int col = bn0 + wn*64 + ni*16 + l15;
      float tm = (EP == 1) ? tma_g[col] : 0.f;
      #pragma unroll
      for (int rg = 0; rg < 4; ++rg){
        int row = bm0 + wm*64 + mi*16 + quad*4 + rg;
        float v = acc[mi][ni][rg];
        if (EP == 1){
          float xv = x[(size_t)row * CC + col];
          float xp = ((row & (TT - 1)) == 0) ? 0.f : x[(size_t)row * CC + col - CC];
          v = xv + (xp - xv) * (v + tm);
        }
        OUT[(size_t)row * CC + col] = f2bf(v);
      }
    }
  }
}

template<int KD, int EP>
__global__ __launch_bounds__(256) void k_gemm_nn_b(const bf16u* __restrict__ A, int lda,
                                                   const bf16u* __restrict__ BT, int koff,
                                                   bf16u* __restrict__ OUT,
                                                   const float* __restrict__ x,
                                                   const float* __restrict__ tma_g){
  __shared__ short As[128 * (KD + 8)];
  __shared__ short Bs[128 * (KD + 8)];
  gemm_nn_body<KD, EP>(A, lda, BT, koff, OUT, x, tma_g, As, Bs,
                       blockIdx.x * 128, blockIdx.y * 128);
}

// 4 xm NN-GEMMs merged into one launch (z = group).
__global__ __launch_bounds__(256) void k_gemm_nn_b4(const bf16u* __restrict__ LO,
                                                    const bf16u* __restrict__ BT,
                                                    bf16u* __restrict__ X0base,
                                                    const float* __restrict__ x,
                                                    const float* __restrict__ tmaa){
  __shared__ short As[128 * 40];
  __shared__ short Bs[128 * 40];
  const int z = blockIdx.z;
  gemm_nn_body<32, 1>(LO + z*32, 128, BT, z*32, X0base + (size_t)z*SLOT,
                      x, tmaa + (size_t)z*CC, As, Bs,
                      blockIdx.x * 128, blockIdx.y * 128);
}

// ---------------------------------------------------------------------------
// LEGACY f32-W GEMMs (fallback path only)
// ---------------------------------------------------------------------------
template<bool OB>
__global__ __launch_bounds__(256) void k_gemm_mfma(const bf16u* __restrict__ X,
                                                   const float* __restrict__ Wa,
                                                   const float* __restrict__ Wb,
                                                   const float* __restrict__ Wc,
                                                   int na, int nab,
                                                   void* __restrict__ OUTv,
                                                   int Nd, int Kd, int act_n){
  __shared__ short As[128 * 40];
  __shared__ short Bs[128 * 40];
  const int tid  = threadIdx.x;
  const int lane = tid & 63;
  const int wv   = tid >> 6;
  const int wm   = wv >> 1, wn = wv & 1;
  const int bn0  = blockIdx.x * 128;
  const int bm0  = blockIdx.y * 128;
  const int l15  = lane & 15;
  const int quad = lane >> 4;

  f32x4 acc[4][4];
  #pragma unroll
  for (int mi = 0; mi < 4; ++mi)
    #pragma unroll
    for (int ni = 0; ni < 4; ++ni)
      #pragma unroll
      for (int rg = 0; rg < 4; ++rg) acc[mi][ni][rg] = 0.f;

  const int r    = tid >> 1;
  const int half = (tid & 1) * 16;

  int rr = bn0 + r;
  const float* wsrc = nullptr;
  if (rr < na)        wsrc = Wa + (size_t)rr * Kd;
  else if (rr < nab)  wsrc = Wb + (size_t)(rr - na) * Kd;
  else if (rr < Nd)   wsrc = Wc + (size_t)(rr - nab) * Kd;
  const bf16u* xsrc = X + (size_t)(bm0 + r) * Kd;

  for (int k0 = 0; k0 < Kd; k0 += 32){
    uint4 xa = *(const uint4*)(xsrc + k0 + half);
    uint4 xb = *(const uint4*)(xsrc + k0 + half + 8);
    uint4 w0 = make_uint4(0,0,0,0), w1 = w0, w2 = w0, w3 = w0;
    if (wsrc){
      w0 = *(const uint4*)(wsrc + k0 + half);
      w1 = *(const uint4*)(wsrc + k0 + half + 4);
      w2 = *(const uint4*)(wsrc + k0 + half + 8);
      w3 = *(const uint4*)(wsrc + k0 + half + 12);
    }
    union { unsigned short s[8]; uint4 v; } p0, p1;
    p0.s[0]=f2bfbits(w0.x); p0.s[1]=f2bfbits(w0.y); p0.s[2]=f2bfbits(w0.z); p0.s[3]=f2bfbits(w0.w);
    p0.s[4]=f2bfbits(w1.x); p0.s[5]=f2bfbits(w1.y); p0.s[6]=f2bfbits(w1.z); p0.s[7]=f2bfbits(w1.w);
    p1.s[0]=f2bfbits(w2.x); p1.s[1]=f2bfbits(w2.y); p1.s[2]=f2bfbits(w2.z); p1.s[3]=f2bfbits(w2.w);
    p1.s[4]=f2bfbits(w3.x); p1.s[5]=f2bfbits(w3.y); p1.s[6]=f2bfbits(w3.z); p1.s[7]=f2bfbits(w3.w);

    *(uint4*)&As[r * 40 + half]     = xa;
    *(uint4*)&As[r * 40 + half + 8] = xb;
    *(uint4*)&Bs[r * 40 + half]     = p0.v;
    *(uint4*)&Bs[r * 40 + half + 8] = p1.v;
    __syncthreads();

    short8 af[4], bfg[4];
    #pragma unroll
    for (int mi = 0; mi < 4; ++mi)
      af[mi] = *(const short8*)&As[(wm*64 + mi*16 + l15) * 40 + quad*8];
    #pragma unroll
    for (int ni = 0; ni < 4; ++ni)
      bfg[ni] = *(const short8*)&Bs[(wn*64 + ni*16 + l15) * 40 + quad*8];
    #pragma unroll
    for (int mi = 0; mi < 4; ++mi)
      #pragma unroll
      for (int ni = 0; ni < 4; ++ni)
        acc[mi][ni] = __builtin_amdgcn_mfma_f32_16x16x32_bf16(af[mi], bfg[ni], acc[mi][ni], 0, 0, 0);
    __syncthreads();
  }

  #pragma unroll
  for (int mi = 0; mi < 4; ++mi){
    #pragma unroll
    for (int ni = 0; ni < 4; ++ni){
      int col = bn0 + wn*64 + ni*16 + l15;
      if (col >= Nd) continue;
      #pragma unroll
      for (int rg = 0; rg < 4; ++rg){
        int row = bm0 + wm*64 + mi*16 + quad*4 + rg;
        float v = acc[mi][ni][rg];
        if (col < act_n) v = tanhf(v);
        if (OB) ((bf16u*)OUTv)[(size_t)row * Nd + col] = f2bf(v);
        else    ((float*)OUTv)[(size_t)row * Nd + col] = v;
      }
    }
  }
}

template<int KD, int EP>
__global__ __launch_bounds__(256) void k_gemm_nn(const bf16u* __restrict__ A, int lda,
                                                 const float* __restrict__ B,
                                                 bf16u* __restrict__ OUT,
                                                 const float* __restrict__ x,
                                                 const float* __restrict__ tma_g){
  __shared__ short As[128 * (KD + 8)];
  __shared__ short Bs[128 * (KD + 8)];
  const int tid  = threadIdx.x;
  const int lane = tid & 63;
  const int wv   = tid >> 6;
  const int wm   = wv >> 1, wn = wv & 1;
  const int bn0  = blockIdx.x * 128;
  const int bm0  = blockIdx.y * 128;
  const int l15  = lane & 15;
  const int quad = lane >> 4;

  for (int idx = tid; idx < 128 * (KD / 8); idx += 256){
    int r  = idx / (KD / 8);
    int kc = (idx % (KD / 8)) * 8;
    *(uint4*)&As[r * (KD + 8) + kc] =
        *(const uint4*)(A + (size_t)(bm0 + r) * lda + kc);
  }
  for (int idx = tid; idx < KD * 128; idx += 256){
    int k = idx >> 7, c = idx & 127;
    Bs[c * (KD + 8) + k] = (short)f2bf(B[(size_t)k * CC + bn0 + c]);
  }
  __syncthreads();

  f32x4 acc[4][4];
  #pragma unroll
  for (int mi = 0; mi < 4; ++mi)
    #pragma unroll
    for (int ni = 0; ni < 4; ++ni)
      #pragma unroll
      for (int rg = 0; rg < 4; ++rg) acc[mi][ni][rg] = 0.f;

  #pragma unroll
  for (int kk = 0; kk < KD; kk += 32){
    short8 af[4], bfg[4];
    #pragma unroll
    for (int mi = 0; mi < 4; ++mi)
      af[mi] = *(const short8*)&As[(wm*64 + mi*16 + l15) * (KD + 8) + kk + quad*8];
    #pragma unroll
    for (int ni = 0; ni < 4; ++ni)
      bfg[ni] = *(const short8*)&Bs[(wn*64 + ni*16 + l15) * (KD + 8) + kk + quad*8];
    #pragma unroll
    for (int mi = 0; mi < 4; ++mi)
      #pragma unroll
      for (int ni = 0; ni < 4; ++ni)
        acc[mi][ni] = __builtin_amdgcn_mfma_f32_16x16x32_bf16(af[mi], bfg[ni], acc[mi][ni], 0, 0, 0);
  }

  #pragma unroll
  for (int mi = 0; mi < 4; ++mi){
    #pragma unroll
    for (int ni = 0; ni < 4; ++ni){
      int col = bn0 + wn*64 + ni*16 + l15;
      float tm = (EP == 1) ? tma_g[col] : 0.f;
      #pragma unroll
      for (int rg = 0; rg < 4; ++rg){
        int row = bm0 + wm*64 + mi*16 + quad*4 + rg;
        float v = acc[mi][ni][rg];
        if (EP == 1){
          float xv = x[(size_t)row * CC + col];
          float xp = ((row & (TT - 1)) == 0) ? 0.f : x[(size_t)row * CC + col - CC];
          v = xv + (xp - xv) * (v + tm);
        }
        OUT[(size_t)row * CC + col] = f2bf(v);
      }
    }
  }
}

// ---------------------------------------------------------------------------
// Fused elementwise + pair precompute + (fast path) Wo/gate_w2 conversion.
// ---------------------------------------------------------------------------
template<int WMODE>
__global__ __launch_bounds__(256) void k_elem(bf16u* __restrict__ K0,
    const bf16u* __restrict__ P1, const bf16u* __restrict__ P2,
    const bf16u* __restrict__ W2A,
    const float* __restrict__ kw2, const float* __restrict__ aw2,
    const float* __restrict__ maw2, const float* __restrict__ mkw2,
    const float* __restrict__ td,  const float* __restrict__ taa,
    const float* __restrict__ tma, const float* __restrict__ tmk,
    const float* __restrict__ faaaa,
    bf16u* __restrict__ KKN, bf16u* __restrict__ Bb, bf16u* __restrict__ UX,
    float* __restrict__ WF,
    bf16u* __restrict__ Rq, float* __restrict__ Dsc, float* __restrict__ RKsc,
    const float* __restrict__ Wo, const float* __restrict__ gate_w2,
    bf16u* __restrict__ WoB, bf16u* __restrict__ GW2T){
  int tid = threadIdx.x;
  if (blockIdx.x >= 1024){
    int blk = blockIdx.x - 1024;
    if (blk < 1024){
      size_t e = ((size_t)blk * 256 + tid) * 4;
      float v[4]; ld4f(Wo + e, v);
      st4bf(WoB + e, v);
    } else {
      int c = (blk - 1024) * 2 + (tid >> 7);
      int j = tid & 127;
      GW2T[(size_t)c * 128 + j] = f2bf(gate_w2[(size_t)j * CC + c]);
    }
    return;
  }
  int n0 = blockIdx.x * 4;
  __shared__ float at_l[4][16], mat_l[4][16], kt_l[4][16], mkt_l[4][16];
  {
    int grp = tid >> 6, q = tid & 63, tt = q >> 4, j = q & 15;
    if (grp == 0)      at_l[tt][j]  = bf2f(P1[(size_t)(n0+tt)*96 + 64 + j]);
    else if (grp == 1) mat_l[tt][j] = bf2f(P1[(size_t)(n0+tt)*96 + 80 + j]);
    else if (grp == 2) kt_l[tt][j]  = bf2f(P2[(size_t)(n0+tt)*32 + j]);
    else               mkt_l[tt][j] = bf2f(P2[(size_t)(n0+tt)*32 + 16 + j]);
  }
  __syncthreads();
  int c  = tid * 4;
  int h  = tid >> 4;       // head (16 lanes per head)
  int lg = tid & 15;

  float kkk[4][4], aa[4][4], mam[4][4], mkm[4][4];
  #pragma unroll
  for (int tt = 0; tt < 4; ++tt)
    #pragma unroll
    for (int i = 0; i < 4; ++i){ kkk[tt][i]=0; aa[tt][i]=0; mam[tt][i]=0; mkm[tt][i]=0; }

  #pragma unroll 4
  for (int j = 0; j < 16; ++j){
    float wk[4], wa[4], wm[4], wq[4];
    ld4f(kw2  + (size_t)j*CC + c, wk);
    ld4f(aw2  + (size_t)j*CC + c, wa);
    ld4f(maw2 + (size_t)j*CC + c, wm);
    ld4f(mkw2 + (size_t)j*CC + c, wq);
    #pragma unroll
    for (int tt = 0; tt < 4; ++tt){
      float s1 = kt_l[tt][j], s2 = at_l[tt][j], s3 = mat_l[tt][j], s4 = mkt_l[tt][j];
      #pragma unroll
      for (int i = 0; i < 4; ++i){
        kkk[tt][i] += s1 * wk[i];
        aa[tt][i]  += s2 * wa[i];
        mam[tt][i] += s3 * wm[i];
        mkm[tt][i] += s4 * wq[i];
      }
    }
  }

  float td4[4], taa4[4], tma4[4], tmk4[4], fa4[4];
  ld4f(td + c, td4); ld4f(taa + c, taa4); ld4f(tma + c, tma4); ld4f(tmk + c, tmk4);
  ld4f(faaaa + c, fa4);

#define ELEM_TOKEN(TT_, E_, A_, B_, KF_, WD_) do{ \
    float k0a[4]; ld4bf(K0 + (E_), k0a); \
    float w2a[4]; ld4bf(W2A + (E_), w2a); \
    float ssq = 0.f; \
    _Pragma("unroll") \
    for (int i = 0; i < 4; ++i){ A_[i] = k0a[i] + kkk[TT_][i]; ssq += A_[i]*A_[i]; } \
    ssq = red16(ssq); \
    float rinv = 1.f / fmaxf(sqrtf(ssq), 1e-12f); \
    float outw_[4]; \
    _Pragma("unroll") \
    for (int i = 0; i < 4; ++i){ \
      float z  = td4[i] + w2a[i]; \
      float nz = -z; \
      float sp = (nz > 15.f) ? nz : log1pf(expf(nz)); \
      float w  = -sp - 0.5f; \
      float av  = sigm(taa4[i] + aa[TT_][i]); \
      float mav = sigm(tma4[i] + mam[TT_][i]); \
      float mkv = sigm(tmk4[i] + mkm[TT_][i]); \
      A_[i] *= rinv; \
      B_[i]  = -A_[i] * av; \
      KF_[i] = k0a[i] * (mav + av * (1.f - mav)) * expf(w * mkv); \
      float ou = -expf(w); \
      outw_[i] = ou; \
      if (WMODE == 1) WD_[i] = __expf(ou);              /* exact f32 w_t */ \
      else            WD_[i] = __expf(hval(f2h(ou)));   /* f16-consistent */ \
    } \
    st4bf(Bb + (E_), B_); \
    st4bf(K0 + (E_), KF_); \
    if (WMODE == 1) *(float4*)(WF + (E_)) = make_float4(WD_[0], WD_[1], WD_[2], WD_[3]); \
    else            st4h(UX + (E_), outw_); \
  }while(0)

  #pragma unroll
  for (int p = 0; p < 2; ++p){
    const int ttE = 2*p, ttO = ttE + 1;
    size_t eE = (size_t)(n0 + ttE) * CC + c;
    size_t eO = eE + CC;
    float aE[4], bE[4], kfE[4], wdE[4];
    float aO[4], bO[4], kfO[4], wdO[4];
    ELEM_TOKEN(ttE, eE, aE, bE, kfE, wdE);
    ELEM_TOKEN(ttO, eO, aO, bO, kfO, wdO);
    st4bf(KKN + eE, aE);

    float rE[4], rO[4];
    ld4bf(Rq + eE, rE); ld4bf(Rq + eO, rO);

    // rk for k_post (before R is overwritten)
    float rkE = red16(rE[0]*kfE[0]*fa4[0] + rE[1]*kfE[1]*fa4[1]
                    + rE[2]*kfE[2]*fa4[2] + rE[3]*kfE[3]*fa4[3]);
    float rkO = red16(rO[0]*kfO[0]*fa4[0] + rO[1]*kfO[1]*fa4[1]
                    + rO[2]*kfO[2]*fa4[2] + rO[3]*kfO[3]*fa4[3]);

    // u1 over KKN odd row
    float c1 = red16(dot4(bE, aO));
    float d  = red16(dot4(kfE, aO));
    float u1[4];
    #pragma unroll
    for (int i = 0; i < 4; ++i) u1[i] = wdE[i]*aO[i] + c1*aE[i];
    st4bf(KKN + eO, u1);

    // q' even
    float cq = red16(dot4(bE, rE));
    float e1 = red16(dot4(kfE, rE));
    float qe[4];
    #pragma unroll
    for (int i = 0; i < 4; ++i) qe[i] = wdE[i]*rE[i] + cq*aE[i];
    st4bf(Rq + eE, qe);

    // z = M_{t+1} q_{t+1}; q' odd = M_t z
    float cz  = red16(dot4(bO, rO));
    float e21 = red16(dot4(kfO, rO));
    float z[4];
    #pragma unroll
    for (int i = 0; i < 4; ++i) z[i] = wdO[i]*rO[i] + cz*aO[i];
    float cy  = red16(dot4(bE, z));
    float e20 = red16(dot4(kfE, z));
    float qo[4];
    #pragma unroll
    for (int i = 0; i < 4; ++i) qo[i] = wdE[i]*z[i] + cy*aE[i];
    st4bf(Rq + eO, qo);

    if (lg == 0){
      size_t pr = (size_t)((n0 + ttE) >> 1);
      float4 dv; dv.x = d; dv.y = e1; dv.z = e20; dv.w = e21;
      *(float4*)(Dsc + (pr * HH + h) * 4) = dv;
      RKsc[(size_t)(n0 + ttE) * HH + h] = rkE;
      RKsc[(size_t)(n0 + ttO) * HH + h] = rkO;
    }
  }
#undef ELEM_TOKEN
}

// ---------------------------------------------------------------------------
// Recurrence v13 (r8-validated): 32-lane rows, 2 waves/SIMD, pair-fused,
// all 4 reductions vs base S, f32 decay (WMODE=1).
// ---------------------------------------------------------------------------
template<int WMODE>
__global__ __launch_bounds__(256) void k_rec(const bf16u* __restrict__ Qp,
                                             const bf16u* __restrict__ WT,
                                             const float* __restrict__ WF,
                                             const bf16u* __restrict__ KFt,
                                             const bf16u* __restrict__ Vt,
                                             const bf16u* __restrict__ Aa,
                                             const bf16u* __restrict__ Bv,
                                             const float* __restrict__ Dsc,
                                             bf16u* __restrict__ Y){
  const int p   = blockIdx.x;                 // 0..511
  const int g   = (p & 7) | ((p >> 6) << 3);  // (b,h) group 0..63, XCD-clustered
  const int oct = (p >> 3) & 7;               // row octet within the head
  const int b   = g >> 4;
  const int h   = g & 15;
  const int tid = threadIdx.x;
  const int l31 = tid & 31;                   // 32 lanes per row
  const int i   = oct * 8 + (tid >> 5);       // state row 0..63
  const size_t base0 = (size_t)(b * TT) * CC + h * HSS;
  const size_t colb  = base0 + l31 * 2;       // 2 cols per lane
  const size_t rowb  = base0 + i;
  const size_t dscb  = ((size_t)(b * (TT/2)) * HH + h) * 4;

  float S0 = 0.f, S1 = 0.f;                   // state cols (2*l31, 2*l31+1)

  unsigned int qEA,qOA,aEA,uOA,kEA,kOA,bEA,bOA,wEA,wOA; float2 fEA,fOA; unsigned short vEA,vOA; float4 dA;
  unsigned int qEB,qOB,aEB,uOB,kEB,kOB,bEB,bOB,wEB,wOB; float2 fEB,fOB; unsigned short vEB,vOB; float4 dB;
  unsigned int qEC,qOC,aEC,uOC,kEC,kOC,bEC,bOC,wEC,wOC; float2 fEC,fOC; unsigned short vEC,vOC; float4 dC;
  unsigned int qED,qOD,aED,uOD,kED,kOD,bED,bOD,wED,wOD; float2 fED,fOD; unsigned short vED,vOD; float4 dD;

#define PL(S, T_) do{ \
    size_t cE_ = colb + (size_t)(T_) * CC, cO_ = cE_ + CC; \
    qE##S = *(const unsigned int*)(Qp  + cE_); qO##S = *(const unsigned int*)(Qp  + cO_); \
    aE##S = *(const unsigned int*)(Aa  + cE_); uO##S = *(const unsigned int*)(Aa  + cO_); \
    kE##S = *(const unsigned int*)(KFt + cE_); kO##S = *(const unsigned int*)(KFt + cO_); \
    bE##S = *(const unsigned int*)(Bv  + cE_); bO##S = *(const unsigned int*)(Bv  + cO_); \
    if (WMODE == 1){ \
      fE##S = *(const float2*)(WF + cE_); fO##S = *(const float2*)(WF + cO_); \
    } else { \
      wE##S = *(const unsigned int*)(WT + cE_); wO##S = *(const unsigned int*)(WT + cO_); \
    } \
    vE##S = Vt[rowb + (size_t)(T_) * CC]; \
    vO##S = Vt[rowb + (size_t)(T_ + 1) * CC]; \
    d##S  = *(const float4*)(Dsc + dscb + (size_t)((T_) >> 1) * (HH*4)); \
  }while(0)

#define PSTEP(S, T_) do{ \
    float a0=bflo(aE##S), a1=bfhi(aE##S); \
    float u0=bflo(uO##S), u1=bfhi(uO##S); \
    float g0=bflo(qE##S), g1=bfhi(qE##S); \
    float o0=bflo(qO##S), o1=bfhi(qO##S); \
    float pE_ = fmaf(S1, a1, S0 * a0); \
    float pO_ = fmaf(S1, u1, S0 * u0); \
    float yE_ = fmaf(S1, g1, S0 * g0); \
    float yO_ = fmaf(S1, o1, S0 * o0); \
    pE_ = red32(pE_); \
    pO_ = red32(pO_); \
    yE_ = red32(yE_); \
    yO_ = red32(yO_); \
    float vEf = bf2f(vE##S), vOf = bf2f(vO##S); \
    float saE = pE_; \
    float saO = fmaf(d##S.x, vEf, pO_); \
    float ypE = fmaf(d##S.y, vEf, yE_); \
    float ypO = fmaf(d##S.z, vEf, fmaf(d##S.w, vOf, yO_)); \
    float k0=bflo(kE##S), k1=bfhi(kE##S); \
    float b0=bflo(bE##S), b1=bfhi(bE##S); \
    float w0, w1; \
    if (WMODE == 1){ w0=fE##S.x; w1=fE##S.y; } \
    else { w0=__expf(hlo(wE##S)); w1=__expf(hhi(wE##S)); } \
    S0 = fmaf(S0, w0, fmaf(saE, b0, vEf * k0)); \
    S1 = fmaf(S1, w1, fmaf(saE, b1, vEf * k1)); \
    float ko0=bflo(kO##S), ko1=bfhi(kO##S); \
    float bo0=bflo(bO##S), bo1=bfhi(bO##S); \
    float wo0, wo1; \
    if (WMODE == 1){ wo0=fO##S.x; wo1=fO##S.y; } \
    else { wo0=__expf(hlo(wO##S)); wo1=__expf(hhi(wO##S)); } \
    S0 = fmaf(S0, wo0, fmaf(saO, bo0, vOf * ko0)); \
    S1 = fmaf(S1, wo1, fmaf(saO, bo1, vOf * ko1)); \
    if (l31 == 0){ \
      Y[rowb + (size_t)(T_) * CC]     = f2bf(ypE); \
      Y[rowb + (size_t)(T_ + 1) * CC] = f2bf(ypO); \
    } \
  }while(0)

  PL(A, 0); PL(B, 2); PL(C, 4); PL(D, 6);
  for (int t = 0; t < TT; t += 8){
    PSTEP(A, t);
    if (t + 8  < TT) PL(A, t + 8);
    PSTEP(B, t + 2);
    if (t + 10 < TT) PL(B, t + 10);
    PSTEP(C, t + 4);
    if (t + 12 < TT) PL(C, t + 12);
    PSTEP(D, t + 6);
    if (t + 14 < TT) PL(D, t + 14);
  }
#undef PL
#undef PSTEP
}

// ---------------------------------------------------------------------------
// Post: GroupNorm + precomputed bonus rk*v + precomputed gate GV -> YG (bf16)
// ---------------------------------------------------------------------------
__global__ __launch_bounds__(256) void k_post(const bf16u* __restrict__ Y,
                                              const bf16u* __restrict__ Vt,
                                              const bf16u* __restrict__ GV,
                                              const float* __restrict__ lnw,
                                              const float* __restrict__ lnb,
                                              const float* __restrict__ RKsc,
                                              bf16u* __restrict__ YG){
  int n = blockIdx.x, tid = threadIdx.x;
  int c = tid * 4;
  size_t e = (size_t)n * CC + c;

  float ya[4]; ld4bf(Y + e, ya);
  float s = ya[0] + ya[1] + ya[2] + ya[3];
  s = red16(s);
  float mu = s * (1.f / 64.f);
  float d[4], vs = 0.f;
  #pragma unroll
  for (int i = 0; i < 4; ++i){ d[i] = ya[i] - mu; vs += d[i] * d[i]; }
  vs = red16(vs);
  float rstd = rsqrtf(vs * (1.f / 64.f) + EPSGN);

  float rk = RKsc[(size_t)n * HH + (tid >> 4)];

  float va[4]; ld4bf(Vt + e, va);
  float lw4[4], lb4[4];
  ld4f(lnw + c, lw4); ld4f(lnb + c, lb4);
  float g[4]; ld4bf(GV + e, g);
  float o[4];
  #pragma unroll
  for (int i = 0; i < 4; ++i){
    float yn = d[i] * rstd * lw4[i] + lb4[i] + rk * va[i];
    o[i] = yn * g[i];
  }
  st4bf(YG + e, o);
}

// ---------------------------------------------------------------------------
extern "C" void kernel_launch(void* const* d_in, const int* in_sizes, int n_in,
                              void* d_out, int out_size, void* d_ws, size_t ws_size,
                              hipStream_t stream){
  (void)in_sizes; (void)n_in; (void)out_size;
  const float* x        = (const float*)d_in[0];
  const float* tmx      = (const float*)d_in[1];
  const float* tmaa     = (const float*)d_in[2];
  const float* maa_w1   = (const float*)d_in[3];
  const float* maa_w2   = (const float*)d_in[4];
  const float* decay_w1 = (const float*)d_in[5];
  const float* decay_w2 = (const float*)d_in[6];
  const float* aaa_w1   = (const float*)d_in[7];
  const float* aaa_w2   = (const float*)d_in[8];
  const float* kkk_w1   = (const float*)d_in[9];
  const float* kkk_w2   = (const float*)d_in[10];
  const float* gate_w1  = (const float*)d_in[11];
  const float* gate_w2  = (const float*)d_in[12];
  const float* ma_w1    = (const float*)d_in[13];
  const float* ma_w2    = (const float*)d_in[14];
  const float* mk_w1    = (const float*)d_in[15];
  const float* mk_w2    = (const float*)d_in[16];
  const float* t_decay  = (const float*)d_in[17];
  const float* t_faaaa  = (const float*)d_in[18];
  const float* t_aaaaa  = (const float*)d_in[19];
  const float* t_misc_a = (const float*)d_in[20];
  const float* t_misc_k = (const float*)d_in[21];
  const float* Wr       = (const float*)d_in[22];
  const float* Wk       = (const float*)d_in[23];
  const float* Wv       = (const float*)d_in[24];
  const float* Wo       = (const float*)d_in[25];
  const float* ln_w     = (const float*)d_in[26];
  const float* ln_b     = (const float*)d_in[27];

  // Slot map (8MiB bf16 each), 56 MiB slots + smalls at 56..60 MiB.
  // 60..76 MiB region time-shared: phase A (weights) -> phase B (WF).
  // WoB/GW2T live in S2 (UX slot, dead in fast path), written by k_elem.
  bf16u* bw  = (bf16u*)d_ws;
  bf16u* MIX = bw + 0*SLOT;
  bf16u* X0  = bw + 0*SLOT;
  bf16u* KKN = bw + 0*SLOT;
  bf16u* YG  = bw + 0*SLOT;
  bf16u* X1  = bw + 1*SLOT;
  bf16u* Bb  = bw + 1*SLOT;
  bf16u* GV  = bw + 1*SLOT;
  bf16u* X2  = bw + 2*SLOT;
  bf16u* UX  = bw + 2*SLOT;
  bf16u* X3  = bw + 3*SLOT;
  bf16u* W2A = bw + 3*SLOT;
  bf16u* Yb  = bw + 3*SLOT;
  bf16u* R   = bw + 4*SLOT;   // becomes q'
  bf16u* K0  = bw + 5*SLOT;   // becomes KF
  bf16u* V   = bw + 6*SLOT;
  char*  wsb = (char*)d_ws;
  bf16u* LO  = (bf16u*)(wsb + (56ull<<20));   // [N,128] bf16, 1 MiB
  bf16u* GT  = (bf16u*)(wsb + (57ull<<20));   // [N,128] bf16, 1 MiB
  bf16u* P1  = (bf16u*)(wsb + (58ull<<20));   // [N,96]  bf16 (dt|at|ma)
  bf16u* P2  = (bf16u*)(wsb + (58ull<<20) + (768ull<<10)); // [N,32] bf16
  float* Dsc = (float*)(wsb + (59ull<<20));   // [N/2,16] float4, 512 KiB
  float* RKsc= (float*)(wsb + (59ull<<20) + (512ull<<10)); // [N,16] f32, 256 KiB
  float* WF  = (float*)(wsb + (60ull<<20));   // [N,CC] f32 w_t, 16 MiB
  bf16u* WrB = (bf16u*)(wsb + (60ull<<20));
  bf16u* WkB = (bf16u*)(wsb + (62ull<<20));
  bf16u* WvB = (bf16u*)(wsb + (64ull<<20));
  bf16u* W1B = (bf16u*)(wsb + (66ull<<20));   // 384 rows x 1024, 0.75 MiB
  bf16u* W2TB= (bf16u*)(wsb + (67ull<<20));   // [1024][192], 0.375 MiB
  bf16u* WoB = UX;                            // S2 (dead in fast path), 2 MiB
  bf16u* GW2T= UX + 1048576;                  // S2 + 2 MiB: [1024][128] bf16
  const bool fast = ws_size >= (77ull<<20);

  if (fast){
    // 0+1. merged mix + weight pre-conversion (bf16; identical RNE rounding)
    k_prep_wconv<<<7744, 256, 0, stream>>>(x, tmx, MIX,
                                           Wr, Wk, Wv, maa_w1, gate_w1, decay_w1,
                                           aaa_w1, ma_w1, kkk_w1, mk_w1,
                                           maa_w2, decay_w2,
                                           WrB, WkB, WvB, W1B, W2TB);
    // 2. lo = tanh(mix @ maa_w1^T)
    k_gemm_b64<true><<<dim3(1,64),256,0,stream>>>(MIX, W1B, LO, 128, CC, 128);
    // 3. xm[g]: 4 NN-GEMMs merged into one launch (grid.z = group)
    k_gemm_nn_b4<<<dim3(8,32,4),256,0,stream>>>(LO, W2TB, X0, x, tmaa);
    // 4. big projections merged: M128 body, 768 blocks = 3 resident/CU
    k_gemm_b128_rkv<<<dim3(8,32,3),256,0,stream>>>(X0, X2, X3, WrB, WkB, WvB,
                                                   R, K0, V);
    // 5. LoRA projections merged into one launch (grid.z = which)
    k_gemm_b64_lora<<<dim3(1,64,3),256,0,stream>>>(X0, X1, X2, W1B, GT, P1, P2);
    // 6. W2A = P1[:, :64] @ decay_w2 (last read of W2TB before WF overwrites)
    k_gemm_nn_b<64,0><<<dim3(8,32),256,0,stream>>>(P1, 96, W2TB, 128, W2A, nullptr, nullptr);
    // 7. fused elementwise + pair precompute + Wo/gate_w2 conversion
    k_elem<1><<<2560, 256, 0, stream>>>(K0, P1, P2, W2A,
                                        kkk_w2, aaa_w2, ma_w2, mk_w2,
                                        t_decay, t_aaaaa, t_misc_a, t_misc_k, t_faaaa,
                                        KKN, Bb, UX, WF, R, Dsc, RKsc,
                                        Wo, gate_w2, WoB, GW2T);
    // 8. delta-rule recurrence (r8-validated v13)
    k_rec<1><<<512, 256, 0, stream>>>(R, UX, WF, K0, V, KKN, Bb, Dsc, Yb);
    // 9. GV = GT @ gate_w2 (BK=64 fast NT path; GW2T from step 7)
    k_gemm_b64<true><<<dim3(8,64),256,0,stream>>>(GT, GW2T, GV, CC, 128, 0);
    // 10. groupnorm + bonus + gate
    k_post<<<4096, 256, 0, stream>>>(Yb, V, GV, ln_w, ln_b, RKsc, YG);
    // 11. out = yg @ Wo^T -> f32 (WoB from step 7, lives in S2)
    k_gemm_b64<false><<<dim3(8,64),256,0,stream>>>(YG, WoB, d_out, CC, CC, 0);
  } else {
    // Fallback: exact r8 sequence (f32 weights in-GEMM, f16 -u decay).
    k_prep<<<4096, 256, 0, stream>>>(x, tmx, MIX);
    k_gemm_mfma<true><<<dim3(1,32),256,0,stream>>>(MIX, maa_w1, maa_w1, maa_w1,
                                                   128, 128, LO, 128, CC, 128);
    bf16u* XMs[4] = {X0, X1, X2, X3};
    for (int g = 0; g < 4; ++g)
      k_gemm_nn<32,1><<<dim3(8,32),256,0,stream>>>(LO + g*32, 128,
                                                   maa_w2 + (size_t)g*32*CC,
                                                   XMs[g], x, tmaa + (size_t)g*CC);
    k_gemm_mfma<true><<<dim3(8,32),256,0,stream>>>(X0, Wr, Wr, Wr, CC, CC, R,  CC, CC, 0);
    k_gemm_mfma<true><<<dim3(8,32),256,0,stream>>>(X2, Wk, Wk, Wk, CC, CC, K0, CC, CC, 0);
    k_gemm_mfma<true><<<dim3(8,32),256,0,stream>>>(X3, Wv, Wv, Wv, CC, CC, V,  CC, CC, 0);
    k_gemm_mfma<true><<<dim3(1,32),256,0,stream>>>(X0, gate_w1, gate_w1, gate_w1,
                                                   128, 128, GT, 128, CC, 128);
    k_gemm_mfma<true><<<dim3(1,32),256,0,stream>>>(X1, decay_w1, aaa_w1, ma_w1,
                                                   64, 80, P1, 96, CC, 64);
    k_gemm_mfma<true><<<dim3(1,32),256,0,stream>>>(X2, kkk_w1, mk_w1, mk_w1,
                                                   16, 32, P2, 32, CC, 16);
    k_gemm_nn<64,0><<<dim3(8,32),256,0,stream>>>(P1, 96, decay_w2, W2A, nullptr, nullptr);
    k_elem<0><<<1024, 256, 0, stream>>>(K0, P1, P2, W2A,
                                        kkk_w2, aaa_w2, ma_w2, mk_w2,
                                        t_decay, t_aaaaa, t_misc_a, t_misc_k, t_faaaa,
                                        KKN, Bb, UX, WF, R, Dsc, RKsc,
                                        Wo, gate_w2, WoB, GW2T);
    k_rec<0><<<512, 256, 0, stream>>>(R, UX, WF, K0, V, KKN, Bb, Dsc, Yb);
    k_gemm_nn<128,0><<<dim3(8,32),256,0,stream>>>(GT, 128, gate_w2, GV, nullptr, nullptr);
    k_post<<<4096, 256, 0, stream>>>(Yb, V, GV, ln_w, ln_b, RKsc, YG);
    k_gemm_mfma<false><<<dim3(8,32),256,0,stream>>>(YG, Wo, Wo, Wo, CC, CC, d_out, CC, CC, 0);
  }
}